// Round 3
// baseline (315.402 us; speedup 1.0000x reference)
//
#include <hip/hip_runtime.h>
#include <hip/hip_bf16.h>

#define S_LEN 2048
#define NHEAD 16
#define HDIM 64
#define HID 1024

typedef __attribute__((ext_vector_type(8))) short bf16x8;
typedef __attribute__((ext_vector_type(4))) float f32x4;

__device__ __forceinline__ unsigned short f2bf(float x) {
    unsigned int u = __builtin_bit_cast(unsigned int, x);
    u = (u + 0x7fffu + ((u >> 16) & 1u)) >> 16;
    return (unsigned short)u;
}
__device__ __forceinline__ float bf2f(unsigned short s) {
    unsigned int u = ((unsigned int)s) << 16;
    return __builtin_bit_cast(float, u);
}

// ---------------- prep: f32 -> bf16 convert (vectorized) ----------------
__global__ void cvt_kernel(const float* __restrict__ src, short* __restrict__ dst, int n4) {
    int i = blockIdx.x * blockDim.x + threadIdx.x;
    if (i < n4) {
        float4 v = reinterpret_cast<const float4*>(src)[i];
        short4 o;
        o.x = (short)f2bf(v.x); o.y = (short)f2bf(v.y);
        o.z = (short)f2bf(v.z); o.w = (short)f2bf(v.w);
        reinterpret_cast<short4*>(dst)[i] = o;
    }
}

// ------------- prep: tiled transpose f32 [R][C] -> bf16 [C][R] ----------
__global__ void transpose_bf16(const float* __restrict__ src, short* __restrict__ dst,
                               int R, int C) {
    __shared__ float tile[32][33];
    int bx = blockIdx.x * 32;  // col base in src
    int by = blockIdx.y * 32;  // row base in src
    int tx = threadIdx.x, ty = threadIdx.y;  // 32 x 8
    #pragma unroll
    for (int i = ty; i < 32; i += 8)
        tile[i][tx] = src[(size_t)(by + i) * C + bx + tx];
    __syncthreads();
    #pragma unroll
    for (int i = ty; i < 32; i += 8)
        dst[(size_t)(bx + i) * R + by + tx] = (short)f2bf(tile[tx][i]);
}

// ---------------- QKV GEMM: [4096,1024] @ [1024,3072] -------------------
// WT layout: [3072 rows n][1024 k] (rows 0..1023 = Wq^T, 1024.. = Wk^T, 2048.. = Wv^T)
__global__ __launch_bounds__(256, 2)
void gemm_qkv(const short* __restrict__ xb, const short* __restrict__ WT,
              const float* __restrict__ bq, const float* __restrict__ bk,
              const float* __restrict__ bv,
              short* __restrict__ Qb, short* __restrict__ Kb, short* __restrict__ Vb) {
    const int LD = 40;
    __shared__ short Al[128 * LD];
    __shared__ short Bl[128 * LD];
    int mb = blockIdx.x, nb = blockIdx.y;
    int tid = threadIdx.x;
    int wave = tid >> 6, lane = tid & 63;
    int wm = wave >> 1, wn = wave & 1;
    int lr = lane & 15, lg = lane >> 4;

    f32x4 acc[4][4] = {};

    for (int ks = 0; ks < 32; ++ks) {
        __syncthreads();
        for (int cid = tid; cid < 512; cid += 256) {
            int r = cid >> 2;
            int c8 = (cid & 3) * 8;
            *(bf16x8*)&Al[r * LD + c8] =
                *(const bf16x8*)&xb[(size_t)(mb * 128 + r) * 1024 + ks * 32 + c8];
            *(bf16x8*)&Bl[r * LD + c8] =
                *(const bf16x8*)&WT[(size_t)(nb * 128 + r) * 1024 + ks * 32 + c8];
        }
        __syncthreads();
        bf16x8 af[4], bfr[4];
        #pragma unroll
        for (int t = 0; t < 4; t++)
            af[t] = *(bf16x8*)&Al[(wm * 64 + t * 16 + lr) * LD + lg * 8];
        #pragma unroll
        for (int t = 0; t < 4; t++)
            bfr[t] = *(bf16x8*)&Bl[(wn * 64 + t * 16 + lr) * LD + lg * 8];
        #pragma unroll
        for (int i = 0; i < 4; i++)
            #pragma unroll
            for (int jn = 0; jn < 4; jn++)
                acc[i][jn] = __builtin_amdgcn_mfma_f32_16x16x32_bf16(af[i], bfr[jn], acc[i][jn], 0, 0, 0);
    }

    #pragma unroll
    for (int jn = 0; jn < 4; jn++) {
        int n = nb * 128 + wn * 64 + jn * 16 + lr;
        int which = n >> 10;
        int n1 = n & 1023;
        const float* bias = (which == 0) ? bq : (which == 1) ? bk : bv;
        short* out = (which == 0) ? Qb : (which == 1) ? Kb : Vb;
        float bv_ = bias[n1];
        #pragma unroll
        for (int i = 0; i < 4; i++) {
            #pragma unroll
            for (int j = 0; j < 4; j++) {
                int mm = mb * 128 + wm * 64 + i * 16 + lg * 4 + j;
                out[(size_t)mm * 1024 + n1] = (short)f2bf(acc[i][jn][j] + bv_);
            }
        }
    }
}

// ---------------- flash attention with antisymmetric flow ---------------
// flow[q,k] = (Q_q.K_k - K_q.Q_k)/8 ; softmax over k ; O = P V
// LD = 66 shorts (33 dwords, odd) -> bank = row + col/2 (mod 32): <=2-way everywhere
__global__ __launch_bounds__(256, 4)
void attn_kernel(const short* __restrict__ Qb, const short* __restrict__ Kb,
                 const short* __restrict__ Vb, short* __restrict__ Fb) {
    const int LD = 66;
    __shared__ short Kt[64 * LD];
    __shared__ short Qt[64 * LD];
    __shared__ short Vt[64 * LD];          // transposed: Vt[dv][key]
    __shared__ short Pl[4][16 * LD];

    int bid = blockIdx.x;
    int qb = bid & 31;
    int h = (bid >> 5) & 15;
    int b = bid >> 9;
    int tid = threadIdx.x;
    int wave = tid >> 6, lane = tid & 63;
    int lr = lane & 15, lg = lane >> 4;

    // ones B-fragment for row-sum MFMA (bf16 1.0 = 0x3F80)
    bf16x8 ones;
    #pragma unroll
    for (int e = 0; e < 8; e++) ones[e] = (short)0x3F80;

    // hoisted per-wave Q/K fragments (A-side), rows = wave's 16 q-rows
    size_t rowbase = ((size_t)(b * S_LEN + qb * 64 + wave * 16 + lr)) * HID + h * HDIM;
    bf16x8 Qf[2], Kf[2];
    #pragma unroll
    for (int c = 0; c < 2; c++) {
        Qf[c] = *(const bf16x8*)(Qb + rowbase + c * 32 + lg * 8);
        Kf[c] = *(const bf16x8*)(Kb + rowbase + c * 32 + lg * 8);
    }

    f32x4 O[4] = {};
    float m[4], l[4];
    #pragma unroll
    for (int j = 0; j < 4; j++) { m[j] = -1e30f; l[j] = 0.f; }

    for (int kt = 0; kt < 32; ++kt) {
        __syncthreads();
        for (int cid = tid; cid < 512; cid += 256) {
            int r = cid >> 3;
            int c8 = (cid & 7) * 8;
            size_t g = ((size_t)(b * S_LEN + kt * 64 + r)) * HID + h * HDIM + c8;
            bf16x8 kv = *(const bf16x8*)(Kb + g);
            bf16x8 qv = *(const bf16x8*)(Qb + g);
            bf16x8 vv = *(const bf16x8*)(Vb + g);
            *(bf16x8*)&Kt[r * LD + c8] = kv;
            *(bf16x8*)&Qt[r * LD + c8] = qv;
            #pragma unroll
            for (int e = 0; e < 8; e++) Vt[(c8 + e) * LD + r] = vv[e];
        }
        __syncthreads();

        f32x4 S1[4] = {}; f32x4 S2[4] = {};
        #pragma unroll
        for (int t = 0; t < 4; t++) {
            #pragma unroll
            for (int c = 0; c < 2; c++) {
                bf16x8 kf = *(bf16x8*)&Kt[(t * 16 + lr) * LD + c * 32 + lg * 8];
                bf16x8 qf = *(bf16x8*)&Qt[(t * 16 + lr) * LD + c * 32 + lg * 8];
                S1[t] = __builtin_amdgcn_mfma_f32_16x16x32_bf16(Qf[c], kf, S1[t], 0, 0, 0);
                S2[t] = __builtin_amdgcn_mfma_f32_16x16x32_bf16(Kf[c], qf, S2[t], 0, 0, 0);
            }
        }

        // online softmax; lane holds rows (lg*4+j), cols (t*16+lr)
        float s[4][4], pm[4];
        #pragma unroll
        for (int j = 0; j < 4; j++) {
            pm[j] = -1e30f;
            #pragma unroll
            for (int t = 0; t < 4; t++) {
                s[t][j] = (S1[t][j] - S2[t][j]) * 0.125f;
                pm[j] = fmaxf(pm[j], s[t][j]);
            }
        }
        #pragma unroll
        for (int off = 1; off < 16; off <<= 1)
            #pragma unroll
            for (int j = 0; j < 4; j++) pm[j] = fmaxf(pm[j], __shfl_xor(pm[j], off));

        // defer-max (T13): only rescale when some row's max grew past m+8
        bool grow = false;
        #pragma unroll
        for (int j = 0; j < 4; j++) grow = grow || (pm[j] > m[j] + 8.f);
        if (__any(grow)) {
            #pragma unroll
            for (int j = 0; j < 4; j++) {
                float mn = fmaxf(m[j], pm[j]);
                float alpha = __expf(m[j] - mn);
                m[j] = mn;
                l[j] *= alpha;
                #pragma unroll
                for (int dvt = 0; dvt < 4; dvt++) O[dvt][j] *= alpha;
            }
        }

        #pragma unroll
        for (int t = 0; t < 4; t++) {
            #pragma unroll
            for (int j = 0; j < 4; j++) {
                float p = __expf(s[t][j] - m[j]);
                Pl[wave][(lg * 4 + j) * LD + t * 16 + lr] = (short)f2bf(p);
            }
        }

        // PV + row-sum via ones-MFMA (replaces 16-lane shuffle sum reduce)
        f32x4 rsum = {};
        #pragma unroll
        for (int c = 0; c < 2; c++) {
            bf16x8 pf = *(bf16x8*)&Pl[wave][lr * LD + c * 32 + lg * 8];
            rsum = __builtin_amdgcn_mfma_f32_16x16x32_bf16(pf, ones, rsum, 0, 0, 0);
            #pragma unroll
            for (int dvt = 0; dvt < 4; dvt++) {
                bf16x8 vf = *(bf16x8*)&Vt[(dvt * 16 + lr) * LD + c * 32 + lg * 8];
                O[dvt] = __builtin_amdgcn_mfma_f32_16x16x32_bf16(pf, vf, O[dvt], 0, 0, 0);
            }
        }
        #pragma unroll
        for (int j = 0; j < 4; j++) l[j] += rsum[j];
    }

    #pragma unroll
    for (int dvt = 0; dvt < 4; dvt++) {
        #pragma unroll
        for (int j = 0; j < 4; j++) {
            int q = qb * 64 + wave * 16 + lg * 4 + j;
            int dv = dvt * 16 + lr;
            float o = O[dvt][j] / l[j];
            Fb[((size_t)(b * S_LEN + q)) * HID + h * HDIM + dv] = (short)f2bf(o);
        }
    }
}

// ------- gate GEMM (K=2048 over [xb | flowed]) + sigmoid + residual -----
// writes y (pre-LN, fp32) directly into d_out; LN then normalizes in place
__global__ __launch_bounds__(256, 2)
void gemm_gate(const short* __restrict__ xb, const short* __restrict__ fb,
               const short* __restrict__ WgT, const float* __restrict__ bg,
               const float* __restrict__ x, float* __restrict__ y) {
    const int LD = 40;
    __shared__ short Al[128 * LD];
    __shared__ short Bl[128 * LD];
    int mb = blockIdx.x, nb = blockIdx.y;
    int tid = threadIdx.x;
    int wave = tid >> 6, lane = tid & 63;
    int wm = wave >> 1, wn = wave & 1;
    int lr = lane & 15, lg = lane >> 4;

    f32x4 acc[4][4] = {};

    for (int ks = 0; ks < 64; ++ks) {
        int kg = ks * 32;
        __syncthreads();
        for (int cid = tid; cid < 512; cid += 256) {
            int r = cid >> 2;
            int c8 = (cid & 3) * 8;
            const short* A = (kg < 1024)
                ? &xb[(size_t)(mb * 128 + r) * 1024 + kg + c8]
                : &fb[(size_t)(mb * 128 + r) * 1024 + (kg - 1024) + c8];
            *(bf16x8*)&Al[r * LD + c8] = *(const bf16x8*)A;
            *(bf16x8*)&Bl[r * LD + c8] =
                *(const bf16x8*)&WgT[(size_t)(nb * 128 + r) * 2048 + kg + c8];
        }
        __syncthreads();
        bf16x8 af[4], bfr[4];
        #pragma unroll
        for (int t = 0; t < 4; t++)
            af[t] = *(bf16x8*)&Al[(wm * 64 + t * 16 + lr) * LD + lg * 8];
        #pragma unroll
        for (int t = 0; t < 4; t++)
            bfr[t] = *(bf16x8*)&Bl[(wn * 64 + t * 16 + lr) * LD + lg * 8];
        #pragma unroll
        for (int i = 0; i < 4; i++)
            #pragma unroll
            for (int jn = 0; jn < 4; jn++)
                acc[i][jn] = __builtin_amdgcn_mfma_f32_16x16x32_bf16(af[i], bfr[jn], acc[i][jn], 0, 0, 0);
    }

    #pragma unroll
    for (int jn = 0; jn < 4; jn++) {
        int n = nb * 128 + wn * 64 + jn * 16 + lr;
        float bgv = bg[n];
        #pragma unroll
        for (int i = 0; i < 4; i++) {
            #pragma unroll
            for (int j = 0; j < 4; j++) {
                int mm = mb * 128 + wm * 64 + i * 16 + lg * 4 + j;
                size_t idx = (size_t)mm * 1024 + n;
                float z = acc[i][jn][j] + bgv;
                float gate = 1.f / (1.f + __expf(-z));
                float fv = bf2f((unsigned short)fb[idx]);
                y[idx] = x[idx] + gate * fv;
            }
        }
    }
}

// ---------------- row LayerNorm in place (fp32 -> fp32) ----------------
__global__ __launch_bounds__(256)
void ln_kernel(float* __restrict__ y, const float* __restrict__ gamma,
               const float* __restrict__ beta) {
    int row = blockIdx.x;
    int tid = threadIdx.x;
    float4 v4 = *(const float4*)&y[(size_t)row * 1024 + tid * 4];
    float v[4] = {v4.x, v4.y, v4.z, v4.w};
    float s = v[0] + v[1] + v[2] + v[3];
    float s2 = v[0]*v[0] + v[1]*v[1] + v[2]*v[2] + v[3]*v[3];
    #pragma unroll
    for (int off = 1; off < 64; off <<= 1) {
        s += __shfl_xor(s, off);
        s2 += __shfl_xor(s2, off);
    }
    __shared__ float red[8];
    int wave = tid >> 6, lane = tid & 63;
    if (lane == 0) { red[wave] = s; red[4 + wave] = s2; }
    __syncthreads();
    s = red[0] + red[1] + red[2] + red[3];
    s2 = red[4] + red[5] + red[6] + red[7];
    float mu = s * (1.f / 1024.f);
    float var = s2 * (1.f / 1024.f) - mu * mu;
    float rsq = rsqrtf(var + 1e-5f);
    float4 o4;
    float* o = (float*)&o4;
    #pragma unroll
    for (int e = 0; e < 4; e++) {
        int n = tid * 4 + e;
        o[e] = (v[e] - mu) * rsq * gamma[n] + beta[n];
    }
    *(float4*)&y[(size_t)row * 1024 + tid * 4] = o4;
}

extern "C" void kernel_launch(void* const* d_in, const int* in_sizes, int n_in,
                              void* d_out, int out_size, void* d_ws, size_t ws_size,
                              hipStream_t stream) {
    const float* x     = (const float*)d_in[0];
    const float* Wq    = (const float*)d_in[1];
    const float* bq    = (const float*)d_in[2];
    const float* Wk    = (const float*)d_in[3];
    const float* bk    = (const float*)d_in[4];
    const float* Wv    = (const float*)d_in[5];
    const float* bv    = (const float*)d_in[6];
    const float* Wg    = (const float*)d_in[7];
    const float* bg    = (const float*)d_in[8];
    const float* gamma = (const float*)d_in[9];
    const float* beta  = (const float*)d_in[10];
    float* out = (float*)d_out;   // reference output is fp32

    char* w = (char*)d_ws;
    const size_t MB = 1024 * 1024;
    short* xb  = (short*)(w + 0 * MB);    // [4096][1024] bf16
    short* Qb  = (short*)(w + 8 * MB);
    short* Kb  = (short*)(w + 16 * MB);
    short* Vb  = (short*)(w + 24 * MB);
    short* WT  = (short*)(w + 32 * MB);   // [3072][1024] bf16 (Wq^T|Wk^T|Wv^T)
    short* WgT = (short*)(w + 38 * MB);   // [1024][2048] bf16
    short* fb  = (short*)(w + 42 * MB);   // flowed bf16 [4096][1024]  (ws ends at 50MB)

    cvt_kernel<<<4096, 256, 0, stream>>>(x, xb, 4096 * 1024 / 4);
    dim3 tb(32, 8);
    transpose_bf16<<<dim3(32, 32), tb, 0, stream>>>(Wq, WT, 1024, 1024);
    transpose_bf16<<<dim3(32, 32), tb, 0, stream>>>(Wk, WT + 1024 * 1024, 1024, 1024);
    transpose_bf16<<<dim3(32, 32), tb, 0, stream>>>(Wv, WT + 2 * 1024 * 1024, 1024, 1024);
    transpose_bf16<<<dim3(32, 64), tb, 0, stream>>>(Wg, WgT, 2048, 1024);
    gemm_qkv<<<dim3(32, 24), 256, 0, stream>>>(xb, WT, bq, bk, bv, Qb, Kb, Vb);
    attn_kernel<<<1024, 256, 0, stream>>>(Qb, Kb, Vb, fb);
    gemm_gate<<<dim3(32, 8), 256, 0, stream>>>(xb, fb, WgT, bg, x, out);
    ln_kernel<<<4096, 256, 0, stream>>>(out, gamma, beta);
}

// Round 5
// 289.211 us; speedup vs baseline: 1.0906x; 1.0906x over previous
//
#include <hip/hip_runtime.h>
#include <hip/hip_bf16.h>

#define S_LEN 2048
#define NHEAD 16
#define HDIM 64
#define HID 1024

typedef __attribute__((ext_vector_type(8))) short bf16x8;
typedef __attribute__((ext_vector_type(4))) float f32x4;

__device__ __forceinline__ unsigned short f2bf(float x) {
    unsigned int u = __builtin_bit_cast(unsigned int, x);
    u = (u + 0x7fffu + ((u >> 16) & 1u)) >> 16;
    return (unsigned short)u;
}
__device__ __forceinline__ float bf2f(unsigned short s) {
    unsigned int u = ((unsigned int)s) << 16;
    return __builtin_bit_cast(float, u);
}

// ---------------- prep: f32 -> bf16 convert (vectorized) ----------------
__global__ void cvt_kernel(const float* __restrict__ src, short* __restrict__ dst, int n4) {
    int i = blockIdx.x * blockDim.x + threadIdx.x;
    if (i < n4) {
        float4 v = reinterpret_cast<const float4*>(src)[i];
        short4 o;
        o.x = (short)f2bf(v.x); o.y = (short)f2bf(v.y);
        o.z = (short)f2bf(v.z); o.w = (short)f2bf(v.w);
        reinterpret_cast<short4*>(dst)[i] = o;
    }
}

// ------------- prep: tiled transpose f32 [R][C] -> bf16 [C][R] ----------
__global__ void transpose_bf16(const float* __restrict__ src, short* __restrict__ dst,
                               int R, int C) {
    __shared__ float tile[32][33];
    int bx = blockIdx.x * 32;  // col base in src
    int by = blockIdx.y * 32;  // row base in src
    int tx = threadIdx.x, ty = threadIdx.y;  // 32 x 8
    #pragma unroll
    for (int i = ty; i < 32; i += 8)
        tile[i][tx] = src[(size_t)(by + i) * C + bx + tx];
    __syncthreads();
    #pragma unroll
    for (int i = ty; i < 32; i += 8)
        dst[(size_t)(bx + i) * R + by + tx] = (short)f2bf(tile[tx][i]);
}

// ----- per-head V transpose: Vb[b*2048+s][h*64+dv] -> VT[(b*16+h)*64+dv][s]
__global__ void vtrans_kernel(const short* __restrict__ Vb, short* __restrict__ VT) {
    __shared__ short tile[32][34];   // 34 shorts: 17-dword stride, conflict-free both ways
    int s0 = blockIdx.x * 32;
    int dv0 = blockIdx.y * 32;
    int bh = blockIdx.z;             // b*16+h
    int b = bh >> 4, h = bh & 15;
    int tx = threadIdx.x, ty = threadIdx.y;  // 32 x 8
    #pragma unroll
    for (int i = ty; i < 32; i += 8)
        tile[i][tx] = Vb[(size_t)(b * S_LEN + s0 + i) * HID + h * HDIM + dv0 + tx];
    __syncthreads();
    #pragma unroll
    for (int i = ty; i < 32; i += 8)
        VT[(size_t)(bh * HDIM + dv0 + i) * S_LEN + s0 + tx] = tile[tx][i];
}

// ---------------- QKV GEMM: [4096,1024] @ [1024,3072] -------------------
// WT layout: [3072 rows n][1024 k] (rows 0..1023 = Wq^T, 1024.. = Wk^T, 2048.. = Wv^T)
__global__ __launch_bounds__(256, 2)
void gemm_qkv(const short* __restrict__ xb, const short* __restrict__ WT,
              const float* __restrict__ bq, const float* __restrict__ bk,
              const float* __restrict__ bv,
              short* __restrict__ Qb, short* __restrict__ Kb, short* __restrict__ Vb) {
    const int LD = 40;
    __shared__ short Al[128 * LD];
    __shared__ short Bl[128 * LD];
    int mb = blockIdx.x, nb = blockIdx.y;
    int tid = threadIdx.x;
    int wave = tid >> 6, lane = tid & 63;
    int wm = wave >> 1, wn = wave & 1;
    int lr = lane & 15, lg = lane >> 4;

    f32x4 acc[4][4] = {};

    for (int ks = 0; ks < 32; ++ks) {
        __syncthreads();
        for (int cid = tid; cid < 512; cid += 256) {
            int r = cid >> 2;
            int c8 = (cid & 3) * 8;
            *(bf16x8*)&Al[r * LD + c8] =
                *(const bf16x8*)&xb[(size_t)(mb * 128 + r) * 1024 + ks * 32 + c8];
            *(bf16x8*)&Bl[r * LD + c8] =
                *(const bf16x8*)&WT[(size_t)(nb * 128 + r) * 1024 + ks * 32 + c8];
        }
        __syncthreads();
        bf16x8 af[4], bfr[4];
        #pragma unroll
        for (int t = 0; t < 4; t++)
            af[t] = *(bf16x8*)&Al[(wm * 64 + t * 16 + lr) * LD + lg * 8];
        #pragma unroll
        for (int t = 0; t < 4; t++)
            bfr[t] = *(bf16x8*)&Bl[(wn * 64 + t * 16 + lr) * LD + lg * 8];
        #pragma unroll
        for (int i = 0; i < 4; i++)
            #pragma unroll
            for (int jn = 0; jn < 4; jn++)
                acc[i][jn] = __builtin_amdgcn_mfma_f32_16x16x32_bf16(af[i], bfr[jn], acc[i][jn], 0, 0, 0);
    }

    #pragma unroll
    for (int jn = 0; jn < 4; jn++) {
        int n = nb * 128 + wn * 64 + jn * 16 + lr;
        int which = n >> 10;
        int n1 = n & 1023;
        const float* bias = (which == 0) ? bq : (which == 1) ? bk : bv;
        short* out = (which == 0) ? Qb : (which == 1) ? Kb : Vb;
        float bv_ = bias[n1];
        #pragma unroll
        for (int i = 0; i < 4; i++) {
            #pragma unroll
            for (int j = 0; j < 4; j++) {
                int mm = mb * 128 + wm * 64 + i * 16 + lg * 4 + j;
                out[(size_t)mm * 1024 + n1] = (short)f2bf(acc[i][jn][j] + bv_);
            }
        }
    }
}

// ---------------- flash attention with antisymmetric flow ---------------
// flow[q,k] = (Q_q.K_k - K_q.Q_k)/8 ; softmax over k ; O = P V
// Transposed-score form: S^T = mfma(tile_rows, wave_rows) so each lane holds a
// FULL q-row (q = lane&15, k = 16t+4lg+j) -> in-lane softmax + 2 shuffles,
// and P stores to LDS are paired b32 (no scalar ds_write_b16 anywhere).
__global__ __launch_bounds__(256, 4)
void attn_kernel(const short* __restrict__ Qb, const short* __restrict__ Kb,
                 const short* __restrict__ VT, short* __restrict__ Fb) {
    const int LD = 66;
    __shared__ short Kt[64 * LD];
    __shared__ short Qt[64 * LD];
    __shared__ short Vt[64 * LD];          // Vt[dv][key] via pre-transposed VT
    __shared__ short Pl[4][16 * LD];       // per-wave P[q][k]

    int bid = blockIdx.x;
    int qb = bid & 31;
    int bh = bid >> 5;                     // b*16+h
    int b = bh >> 4, h = bh & 15;
    int tid = threadIdx.x;
    int wave = tid >> 6, lane = tid & 63;
    int lr = lane & 15, lg = lane >> 4;

    // hoisted per-wave Q/K fragments (B-side now), rows = wave's 16 q-rows
    size_t rowbase = ((size_t)(b * S_LEN + qb * 64 + wave * 16 + lr)) * HID + h * HDIM;
    bf16x8 Qf[2], Kf[2];
    #pragma unroll
    for (int c = 0; c < 2; c++) {
        Qf[c] = *(const bf16x8*)(Qb + rowbase + c * 32 + lg * 8);
        Kf[c] = *(const bf16x8*)(Kb + rowbase + c * 32 + lg * 8);
    }

    const short* VTb = VT + (size_t)bh * HDIM * S_LEN;

    f32x4 O[4] = {};
    float m = -1e30f, l = 0.f;   // per-lane softmax state for q = lr

    for (int kt = 0; kt < 32; ++kt) {
        __syncthreads();
        for (int cid = tid; cid < 512; cid += 256) {
            int r = cid >> 3;
            int c8 = (cid & 7) * 8;
            size_t g = ((size_t)(b * S_LEN + kt * 64 + r)) * HID + h * HDIM + c8;
            *(bf16x8*)&Kt[r * LD + c8] = *(const bf16x8*)(Kb + g);
            *(bf16x8*)&Qt[r * LD + c8] = *(const bf16x8*)(Qb + g);
            *(bf16x8*)&Vt[r * LD + c8] =
                *(const bf16x8*)(VTb + (size_t)r * S_LEN + kt * 64 + c8);
        }
        __syncthreads();

        // S^T blocks: D[m=key][n=q]; dot commutes so values = S1/S2
        f32x4 S1[4] = {}; f32x4 S2[4] = {};
        #pragma unroll
        for (int t = 0; t < 4; t++) {
            #pragma unroll
            for (int c = 0; c < 2; c++) {
                bf16x8 kf = *(bf16x8*)&Kt[(t * 16 + lr) * LD + c * 32 + lg * 8];
                bf16x8 qf = *(bf16x8*)&Qt[(t * 16 + lr) * LD + c * 32 + lg * 8];
                S1[t] = __builtin_amdgcn_mfma_f32_16x16x32_bf16(kf, Qf[c], S1[t], 0, 0, 0);
                S2[t] = __builtin_amdgcn_mfma_f32_16x16x32_bf16(qf, Kf[c], S2[t], 0, 0, 0);
            }
        }

        // lane holds q = lr, keys k = 16t + 4lg + j
        float s[4][4];
        float pm = -1e30f;
        #pragma unroll
        for (int t = 0; t < 4; t++)
            #pragma unroll
            for (int j = 0; j < 4; j++) {
                s[t][j] = (S1[t][j] - S2[t][j]) * 0.125f;
                pm = fmaxf(pm, s[t][j]);
            }
        pm = fmaxf(pm, __shfl_xor(pm, 16));
        pm = fmaxf(pm, __shfl_xor(pm, 32));

        // defer-max (T13): rescale only when row max grew past m+8
        if (__any(pm > m + 8.f)) {
            float mn = fmaxf(m, pm);
            float alpha = __expf(m - mn);
            m = mn;
            l *= alpha;
            float a[4];
            #pragma unroll
            for (int j = 0; j < 4; j++) a[j] = __shfl(alpha, lg * 4 + j);
            #pragma unroll
            for (int dvt = 0; dvt < 4; dvt++)
                #pragma unroll
                for (int j = 0; j < 4; j++) O[dvt][j] *= a[j];
        }

        float rs = 0.f;
        #pragma unroll
        for (int t = 0; t < 4; t++) {
            float p0 = __expf(s[t][0] - m);
            float p1 = __expf(s[t][1] - m);
            float p2 = __expf(s[t][2] - m);
            float p3 = __expf(s[t][3] - m);
            rs += (p0 + p1) + (p2 + p3);
            unsigned w0 = (unsigned)f2bf(p0) | ((unsigned)f2bf(p1) << 16);
            unsigned w1 = (unsigned)f2bf(p2) | ((unsigned)f2bf(p3) << 16);
            *(unsigned*)&Pl[wave][lr * LD + 16 * t + 4 * lg]     = w0;
            *(unsigned*)&Pl[wave][lr * LD + 16 * t + 4 * lg + 2] = w1;
        }
        rs += __shfl_xor(rs, 16);
        rs += __shfl_xor(rs, 32);
        l += rs;

        // PV: A = P rows (q = lane&15), B = Vt rows (dv)
        #pragma unroll
        for (int c = 0; c < 2; c++) {
            bf16x8 pf = *(bf16x8*)&Pl[wave][lr * LD + c * 32 + lg * 8];
            #pragma unroll
            for (int dvt = 0; dvt < 4; dvt++) {
                bf16x8 vf = *(bf16x8*)&Vt[(dvt * 16 + lr) * LD + c * 32 + lg * 8];
                O[dvt] = __builtin_amdgcn_mfma_f32_16x16x32_bf16(pf, vf, O[dvt], 0, 0, 0);
            }
        }
    }

    float linv = 1.f / l;
    float li[4];
    #pragma unroll
    for (int j = 0; j < 4; j++) li[j] = __shfl(linv, lg * 4 + j);
    #pragma unroll
    for (int dvt = 0; dvt < 4; dvt++) {
        #pragma unroll
        for (int j = 0; j < 4; j++) {
            int q = qb * 64 + wave * 16 + lg * 4 + j;
            int dv = dvt * 16 + lr;
            Fb[((size_t)(b * S_LEN + q)) * HID + h * HDIM + dv] =
                (short)f2bf(O[dvt][j] * li[j]);
        }
    }
}

// ------- gate GEMM (K=2048 over [xb | flowed]) + sigmoid + residual -----
// writes y (pre-LN, fp32) directly into d_out; LN then normalizes in place
__global__ __launch_bounds__(256, 2)
void gemm_gate(const short* __restrict__ xb, const short* __restrict__ fb,
               const short* __restrict__ WgT, const float* __restrict__ bg,
               const float* __restrict__ x, float* __restrict__ y) {
    const int LD = 40;
    __shared__ short Al[128 * LD];
    __shared__ short Bl[128 * LD];
    int mb = blockIdx.x, nb = blockIdx.y;
    int tid = threadIdx.x;
    int wave = tid >> 6, lane = tid & 63;
    int wm = wave >> 1, wn = wave & 1;
    int lr = lane & 15, lg = lane >> 4;

    f32x4 acc[4][4] = {};

    for (int ks = 0; ks < 64; ++ks) {
        int kg = ks * 32;
        __syncthreads();
        for (int cid = tid; cid < 512; cid += 256) {
            int r = cid >> 2;
            int c8 = (cid & 3) * 8;
            const short* A = (kg < 1024)
                ? &xb[(size_t)(mb * 128 + r) * 1024 + kg + c8]
                : &fb[(size_t)(mb * 128 + r) * 1024 + (kg - 1024) + c8];
            *(bf16x8*)&Al[r * LD + c8] = *(const bf16x8*)A;
            *(bf16x8*)&Bl[r * LD + c8] =
                *(const bf16x8*)&WgT[(size_t)(nb * 128 + r) * 2048 + kg + c8];
        }
        __syncthreads();
        bf16x8 af[4], bfr[4];
        #pragma unroll
        for (int t = 0; t < 4; t++)
            af[t] = *(bf16x8*)&Al[(wm * 64 + t * 16 + lr) * LD + lg * 8];
        #pragma unroll
        for (int t = 0; t < 4; t++)
            bfr[t] = *(bf16x8*)&Bl[(wn * 64 + t * 16 + lr) * LD + lg * 8];
        #pragma unroll
        for (int i = 0; i < 4; i++)
            #pragma unroll
            for (int jn = 0; jn < 4; jn++)
                acc[i][jn] = __builtin_amdgcn_mfma_f32_16x16x32_bf16(af[i], bfr[jn], acc[i][jn], 0, 0, 0);
    }

    #pragma unroll
    for (int jn = 0; jn < 4; jn++) {
        int n = nb * 128 + wn * 64 + jn * 16 + lr;
        float bgv = bg[n];
        #pragma unroll
        for (int i = 0; i < 4; i++) {
            #pragma unroll
            for (int j = 0; j < 4; j++) {
                int mm = mb * 128 + wm * 64 + i * 16 + lg * 4 + j;
                size_t idx = (size_t)mm * 1024 + n;
                float z = acc[i][jn][j] + bgv;
                float gate = 1.f / (1.f + __expf(-z));
                float fv = bf2f((unsigned short)fb[idx]);
                y[idx] = x[idx] + gate * fv;
            }
        }
    }
}

// ---------------- row LayerNorm in place (fp32 -> fp32) ----------------
__global__ __launch_bounds__(256)
void ln_kernel(float* __restrict__ y, const float* __restrict__ gamma,
               const float* __restrict__ beta) {
    int row = blockIdx.x;
    int tid = threadIdx.x;
    float4 v4 = *(const float4*)&y[(size_t)row * 1024 + tid * 4];
    float v[4] = {v4.x, v4.y, v4.z, v4.w};
    float s = v[0] + v[1] + v[2] + v[3];
    float s2 = v[0]*v[0] + v[1]*v[1] + v[2]*v[2] + v[3]*v[3];
    #pragma unroll
    for (int off = 1; off < 64; off <<= 1) {
        s += __shfl_xor(s, off);
        s2 += __shfl_xor(s2, off);
    }
    __shared__ float red[8];
    int wave = tid >> 6, lane = tid & 63;
    if (lane == 0) { red[wave] = s; red[4 + wave] = s2; }
    __syncthreads();
    s = red[0] + red[1] + red[2] + red[3];
    s2 = red[4] + red[5] + red[6] + red[7];
    float mu = s * (1.f / 1024.f);
    float var = s2 * (1.f / 1024.f) - mu * mu;
    float rsq = rsqrtf(var + 1e-5f);
    float4 o4;
    float* o = (float*)&o4;
    #pragma unroll
    for (int e = 0; e < 4; e++) {
        int n = tid * 4 + e;
        o[e] = (v[e] - mu) * rsq * gamma[n] + beta[n];
    }
    *(float4*)&y[(size_t)row * 1024 + tid * 4] = o4;
}

extern "C" void kernel_launch(void* const* d_in, const int* in_sizes, int n_in,
                              void* d_out, int out_size, void* d_ws, size_t ws_size,
                              hipStream_t stream) {
    const float* x     = (const float*)d_in[0];
    const float* Wq    = (const float*)d_in[1];
    const float* bq    = (const float*)d_in[2];
    const float* Wk    = (const float*)d_in[3];
    const float* bk    = (const float*)d_in[4];
    const float* Wv    = (const float*)d_in[5];
    const float* bv    = (const float*)d_in[6];
    const float* Wg    = (const float*)d_in[7];
    const float* bg    = (const float*)d_in[8];
    const float* gamma = (const float*)d_in[9];
    const float* beta  = (const float*)d_in[10];
    float* out = (float*)d_out;   // reference output is fp32

    char* w = (char*)d_ws;
    const size_t MB = 1024 * 1024;
    short* xb  = (short*)(w + 0 * MB);    // [4096][1024] bf16
    short* Qb  = (short*)(w + 8 * MB);
    short* Kb  = (short*)(w + 16 * MB);
    short* Vb  = (short*)(w + 24 * MB);
    short* WT  = (short*)(w + 32 * MB);   // [3072][1024] bf16 (Wq^T|Wk^T|Wv^T)
    short* WgT = (short*)(w + 38 * MB);   // [1024][2048] bf16
    short* fb  = (short*)(w + 42 * MB);   // flowed bf16 [4096][1024]
    short* VT  = (short*)(w + 50 * MB);   // V^T per head [b*16+h][64 dv][2048 s] (8MB)

    cvt_kernel<<<4096, 256, 0, stream>>>(x, xb, 4096 * 1024 / 4);
    dim3 tb(32, 8);
    transpose_bf16<<<dim3(32, 32), tb, 0, stream>>>(Wq, WT, 1024, 1024);
    transpose_bf16<<<dim3(32, 32), tb, 0, stream>>>(Wk, WT + 1024 * 1024, 1024, 1024);
    transpose_bf16<<<dim3(32, 32), tb, 0, stream>>>(Wv, WT + 2 * 1024 * 1024, 1024, 1024);
    transpose_bf16<<<dim3(32, 64), tb, 0, stream>>>(Wg, WgT, 2048, 1024);
    gemm_qkv<<<dim3(32, 24), 256, 0, stream>>>(xb, WT, bq, bk, bv, Qb, Kb, Vb);
    vtrans_kernel<<<dim3(64, 2, 32), tb, 0, stream>>>(Vb, VT);
    attn_kernel<<<1024, 256, 0, stream>>>(Qb, Kb, VT, fb);
    gemm_gate<<<dim3(32, 8), 256, 0, stream>>>(xb, fb, WgT, bg, x, out);
    ln_kernel<<<4096, 256, 0, stream>>>(out, gamma, beta);
}

// Round 6
// 240.248 us; speedup vs baseline: 1.3128x; 1.2038x over previous
//
#include <hip/hip_runtime.h>
#include <hip/hip_bf16.h>

#define S_LEN 2048
#define NHEAD 16
#define HDIM 64
#define HID 1024

typedef __attribute__((ext_vector_type(8))) short bf16x8;
typedef __attribute__((ext_vector_type(4))) float f32x4;
typedef __attribute__((ext_vector_type(2))) unsigned int u32x2;

__device__ __forceinline__ unsigned short f2bf(float x) {
    unsigned int u = __builtin_bit_cast(unsigned int, x);
    u = (u + 0x7fffu + ((u >> 16) & 1u)) >> 16;
    return (unsigned short)u;
}
__device__ __forceinline__ float bf2f(unsigned short s) {
    unsigned int u = ((unsigned int)s) << 16;
    return __builtin_bit_cast(float, u);
}

// ---------------- prep: f32 -> bf16 convert (vectorized) ----------------
__global__ void cvt_kernel(const float* __restrict__ src, short* __restrict__ dst, int n4) {
    int i = blockIdx.x * blockDim.x + threadIdx.x;
    if (i < n4) {
        float4 v = reinterpret_cast<const float4*>(src)[i];
        short4 o;
        o.x = (short)f2bf(v.x); o.y = (short)f2bf(v.y);
        o.z = (short)f2bf(v.z); o.w = (short)f2bf(v.w);
        reinterpret_cast<short4*>(dst)[i] = o;
    }
}

// ------------- prep: tiled transpose f32 [R][C] -> bf16 [C][R] ----------
__global__ void transpose_bf16(const float* __restrict__ src, short* __restrict__ dst,
                               int R, int C) {
    __shared__ float tile[32][33];
    int bx = blockIdx.x * 32;  // col base in src
    int by = blockIdx.y * 32;  // row base in src
    int tx = threadIdx.x, ty = threadIdx.y;  // 32 x 8
    #pragma unroll
    for (int i = ty; i < 32; i += 8)
        tile[i][tx] = src[(size_t)(by + i) * C + bx + tx];
    __syncthreads();
    #pragma unroll
    for (int i = ty; i < 32; i += 8)
        dst[(size_t)(bx + i) * R + by + tx] = (short)f2bf(tile[tx][i]);
}

// ----- per-head V transpose: Vb[b*2048+s][h*64+dv] -> VT[(b*16+h)*64+dv][s]
__global__ void vtrans_kernel(const short* __restrict__ Vb, short* __restrict__ VT) {
    __shared__ short tile[32][34];   // 34 shorts: 17-dword stride, conflict-free both ways
    int s0 = blockIdx.x * 32;
    int dv0 = blockIdx.y * 32;
    int bh = blockIdx.z;             // b*16+h
    int b = bh >> 4, h = bh & 15;
    int tx = threadIdx.x, ty = threadIdx.y;  // 32 x 8
    #pragma unroll
    for (int i = ty; i < 32; i += 8)
        tile[i][tx] = Vb[(size_t)(b * S_LEN + s0 + i) * HID + h * HDIM + dv0 + tx];
    __syncthreads();
    #pragma unroll
    for (int i = ty; i < 32; i += 8)
        VT[(size_t)(bh * HDIM + dv0 + i) * S_LEN + s0 + tx] = tile[tx][i];
}

// ---------------- QKV GEMM: [4096,1024] @ [1024,3072] -------------------
// WT layout: [3072 rows n][1024 k] (rows 0..1023 = Wq^T, 1024.. = Wk^T, 2048.. = Wv^T)
__global__ __launch_bounds__(256, 2)
void gemm_qkv(const short* __restrict__ xb, const short* __restrict__ WT,
              const float* __restrict__ bq, const float* __restrict__ bk,
              const float* __restrict__ bv,
              short* __restrict__ Qb, short* __restrict__ Kb, short* __restrict__ Vb) {
    const int LD = 40;
    __shared__ short Al[128 * LD];
    __shared__ short Bl[128 * LD];
    int mb = blockIdx.x, nb = blockIdx.y;
    int tid = threadIdx.x;
    int wave = tid >> 6, lane = tid & 63;
    int wm = wave >> 1, wn = wave & 1;
    int lr = lane & 15, lg = lane >> 4;

    f32x4 acc[4][4] = {};

    for (int ks = 0; ks < 32; ++ks) {
        __syncthreads();
        for (int cid = tid; cid < 512; cid += 256) {
            int r = cid >> 2;
            int c8 = (cid & 3) * 8;
            *(bf16x8*)&Al[r * LD + c8] =
                *(const bf16x8*)&xb[(size_t)(mb * 128 + r) * 1024 + ks * 32 + c8];
            *(bf16x8*)&Bl[r * LD + c8] =
                *(const bf16x8*)&WT[(size_t)(nb * 128 + r) * 1024 + ks * 32 + c8];
        }
        __syncthreads();
        bf16x8 af[4], bfr[4];
        #pragma unroll
        for (int t = 0; t < 4; t++)
            af[t] = *(bf16x8*)&Al[(wm * 64 + t * 16 + lr) * LD + lg * 8];
        #pragma unroll
        for (int t = 0; t < 4; t++)
            bfr[t] = *(bf16x8*)&Bl[(wn * 64 + t * 16 + lr) * LD + lg * 8];
        #pragma unroll
        for (int i = 0; i < 4; i++)
            #pragma unroll
            for (int jn = 0; jn < 4; jn++)
                acc[i][jn] = __builtin_amdgcn_mfma_f32_16x16x32_bf16(af[i], bfr[jn], acc[i][jn], 0, 0, 0);
    }

    #pragma unroll
    for (int jn = 0; jn < 4; jn++) {
        int n = nb * 128 + wn * 64 + jn * 16 + lr;
        int which = n >> 10;
        int n1 = n & 1023;
        const float* bias = (which == 0) ? bq : (which == 1) ? bk : bv;
        short* out = (which == 0) ? Qb : (which == 1) ? Kb : Vb;
        float bv_ = bias[n1];
        #pragma unroll
        for (int i = 0; i < 4; i++) {
            #pragma unroll
            for (int j = 0; j < 4; j++) {
                int mm = mb * 128 + wm * 64 + i * 16 + lg * 4 + j;
                out[(size_t)mm * 1024 + n1] = (short)f2bf(acc[i][jn][j] + bv_);
            }
        }
    }
}

// ---------------- flash attention with antisymmetric flow ---------------
// flow[q,k] = (Q_q.K_k - K_q.Q_k)/8 ; softmax over k ; O = P V
// Linear [64][64]-short tiles (128B rows) + T2 XOR swizzle: 16B-chunk index
// XORed with (row&7). All b128 staging writes, fragment reads, and the b64
// P writes are bank-conflict-free under the 8-lane/cycle service model.
__global__ __launch_bounds__(256, 4)
void attn_kernel(const short* __restrict__ Qb, const short* __restrict__ Kb,
                 const short* __restrict__ VT, short* __restrict__ Fb) {
    __shared__ short Kt[64 * 64];
    __shared__ short Qt[64 * 64];
    __shared__ short Vt[64 * 64];          // Vt[dv][key] via pre-transposed VT
    __shared__ short Pl[4][16 * 64];       // per-wave P[q][k], swizzled

    int bid = blockIdx.x;
    int qb = bid & 31;
    int bh = bid >> 5;                     // b*16+h
    int b = bh >> 4, h = bh & 15;
    int tid = threadIdx.x;
    int wave = tid >> 6, lane = tid & 63;
    int lr = lane & 15, lg = lane >> 4;

    // hoisted per-wave Q/K fragments (B-side), rows = wave's 16 q-rows
    size_t rowbase = ((size_t)(b * S_LEN + qb * 64 + wave * 16 + lr)) * HID + h * HDIM;
    bf16x8 Qf[2], Kf[2];
    #pragma unroll
    for (int c = 0; c < 2; c++) {
        Qf[c] = *(const bf16x8*)(Qb + rowbase + c * 32 + lg * 8);
        Kf[c] = *(const bf16x8*)(Kb + rowbase + c * 32 + lg * 8);
    }

    const short* VTb = VT + (size_t)bh * HDIM * S_LEN;

    f32x4 O[4] = {};
    float m = -1e30f, l = 0.f;   // per-lane softmax state for q = lr

    for (int kt = 0; kt < 32; ++kt) {
        __syncthreads();
        for (int cid = tid; cid < 512; cid += 256) {
            int r = cid >> 3;
            int c = cid & 7;                       // 16B chunk within row
            int dsts = r * 64 + ((c ^ (r & 7)) * 8);  // swizzled dest (shorts)
            size_t g = ((size_t)(b * S_LEN + kt * 64 + r)) * HID + h * HDIM + c * 8;
            *(bf16x8*)&Kt[dsts] = *(const bf16x8*)(Kb + g);
            *(bf16x8*)&Qt[dsts] = *(const bf16x8*)(Qb + g);
            *(bf16x8*)&Vt[dsts] =
                *(const bf16x8*)(VTb + (size_t)r * S_LEN + kt * 64 + c * 8);
        }
        __syncthreads();

        // S^T blocks: D[m=key][n=q]; dot commutes so values = S1/S2
        f32x4 S1[4] = {}; f32x4 S2[4] = {};
        #pragma unroll
        for (int t = 0; t < 4; t++) {
            #pragma unroll
            for (int c = 0; c < 2; c++) {
                int fo = (t * 16 + lr) * 64 + (((4 * c + lg) ^ (lr & 7)) * 8);
                bf16x8 kf = *(bf16x8*)&Kt[fo];
                bf16x8 qf = *(bf16x8*)&Qt[fo];
                S1[t] = __builtin_amdgcn_mfma_f32_16x16x32_bf16(kf, Qf[c], S1[t], 0, 0, 0);
                S2[t] = __builtin_amdgcn_mfma_f32_16x16x32_bf16(qf, Kf[c], S2[t], 0, 0, 0);
            }
        }

        // lane holds q = lr, keys k = 16t + 4lg + j
        float s[4][4];
        float pm = -1e30f;
        #pragma unroll
        for (int t = 0; t < 4; t++)
            #pragma unroll
            for (int j = 0; j < 4; j++) {
                s[t][j] = (S1[t][j] - S2[t][j]) * 0.125f;
                pm = fmaxf(pm, s[t][j]);
            }
        pm = fmaxf(pm, __shfl_xor(pm, 16));
        pm = fmaxf(pm, __shfl_xor(pm, 32));

        // defer-max (T13): rescale only when row max grew past m+8
        if (__any(pm > m + 8.f)) {
            float mn = fmaxf(m, pm);
            float alpha = __expf(m - mn);
            m = mn;
            l *= alpha;
            float a[4];
            #pragma unroll
            for (int j = 0; j < 4; j++) a[j] = __shfl(alpha, lg * 4 + j);
            #pragma unroll
            for (int dvt = 0; dvt < 4; dvt++)
                #pragma unroll
                for (int j = 0; j < 4; j++) O[dvt][j] *= a[j];
        }

        float rs = 0.f;
        #pragma unroll
        for (int t = 0; t < 4; t++) {
            float p0 = __expf(s[t][0] - m);
            float p1 = __expf(s[t][1] - m);
            float p2 = __expf(s[t][2] - m);
            float p3 = __expf(s[t][3] - m);
            rs += (p0 + p1) + (p2 + p3);
            // P[q=lr][k=16t+4lg+0..3] -> single b64 at swizzled chunk
            u32x2 pw;
            pw[0] = (unsigned)f2bf(p0) | ((unsigned)f2bf(p1) << 16);
            pw[1] = (unsigned)f2bf(p2) | ((unsigned)f2bf(p3) << 16);
            int po = lr * 64 + (((2 * t + (lg >> 1)) ^ (lr & 7)) * 8) + (lg & 1) * 4;
            *(u32x2*)&Pl[wave][po] = pw;
        }
        rs += __shfl_xor(rs, 16);
        rs += __shfl_xor(rs, 32);
        l += rs;

        // PV: A = P rows (q = lane&15), B = Vt rows (dv)
        #pragma unroll
        for (int c = 0; c < 2; c++) {
            bf16x8 pf = *(bf16x8*)&Pl[wave][lr * 64 + (((4 * c + lg) ^ (lr & 7)) * 8)];
            #pragma unroll
            for (int dvt = 0; dvt < 4; dvt++) {
                bf16x8 vf = *(bf16x8*)&Vt[(dvt * 16 + lr) * 64 + (((4 * c + lg) ^ (lr & 7)) * 8)];
                O[dvt] = __builtin_amdgcn_mfma_f32_16x16x32_bf16(pf, vf, O[dvt], 0, 0, 0);
            }
        }
    }

    float linv = 1.f / l;
    float li[4];
    #pragma unroll
    for (int j = 0; j < 4; j++) li[j] = __shfl(linv, lg * 4 + j);
    #pragma unroll
    for (int dvt = 0; dvt < 4; dvt++) {
        #pragma unroll
        for (int j = 0; j < 4; j++) {
            int q = qb * 64 + wave * 16 + lg * 4 + j;
            int dv = dvt * 16 + lr;
            Fb[((size_t)(b * S_LEN + q)) * HID + h * HDIM + dv] =
                (short)f2bf(O[dvt][j] * li[j]);
        }
    }
}

// ------- gate GEMM (K=2048 over [xb | flowed]) + sigmoid + residual -----
// writes y (pre-LN, fp32) directly into d_out; LN then normalizes in place
__global__ __launch_bounds__(256, 2)
void gemm_gate(const short* __restrict__ xb, const short* __restrict__ fb,
               const short* __restrict__ WgT, const float* __restrict__ bg,
               const float* __restrict__ x, float* __restrict__ y) {
    const int LD = 40;
    __shared__ short Al[128 * LD];
    __shared__ short Bl[128 * LD];
    int mb = blockIdx.x, nb = blockIdx.y;
    int tid = threadIdx.x;
    int wave = tid >> 6, lane = tid & 63;
    int wm = wave >> 1, wn = wave & 1;
    int lr = lane & 15, lg = lane >> 4;

    f32x4 acc[4][4] = {};

    for (int ks = 0; ks < 64; ++ks) {
        int kg = ks * 32;
        __syncthreads();
        for (int cid = tid; cid < 512; cid += 256) {
            int r = cid >> 2;
            int c8 = (cid & 3) * 8;
            const short* A = (kg < 1024)
                ? &xb[(size_t)(mb * 128 + r) * 1024 + kg + c8]
                : &fb[(size_t)(mb * 128 + r) * 1024 + (kg - 1024) + c8];
            *(bf16x8*)&Al[r * LD + c8] = *(const bf16x8*)A;
            *(bf16x8*)&Bl[r * LD + c8] =
                *(const bf16x8*)&WgT[(size_t)(nb * 128 + r) * 2048 + kg + c8];
        }
        __syncthreads();
        bf16x8 af[4], bfr[4];
        #pragma unroll
        for (int t = 0; t < 4; t++)
            af[t] = *(bf16x8*)&Al[(wm * 64 + t * 16 + lr) * LD + lg * 8];
        #pragma unroll
        for (int t = 0; t < 4; t++)
            bfr[t] = *(bf16x8*)&Bl[(wn * 64 + t * 16 + lr) * LD + lg * 8];
        #pragma unroll
        for (int i = 0; i < 4; i++)
            #pragma unroll
            for (int jn = 0; jn < 4; jn++)
                acc[i][jn] = __builtin_amdgcn_mfma_f32_16x16x32_bf16(af[i], bfr[jn], acc[i][jn], 0, 0, 0);
    }

    #pragma unroll
    for (int jn = 0; jn < 4; jn++) {
        int n = nb * 128 + wn * 64 + jn * 16 + lr;
        float bgv = bg[n];
        #pragma unroll
        for (int i = 0; i < 4; i++) {
            #pragma unroll
            for (int j = 0; j < 4; j++) {
                int mm = mb * 128 + wm * 64 + i * 16 + lg * 4 + j;
                size_t idx = (size_t)mm * 1024 + n;
                float z = acc[i][jn][j] + bgv;
                float gate = 1.f / (1.f + __expf(-z));
                float fv = bf2f((unsigned short)fb[idx]);
                y[idx] = x[idx] + gate * fv;
            }
        }
    }
}

// ---------------- row LayerNorm in place (fp32 -> fp32) ----------------
__global__ __launch_bounds__(256)
void ln_kernel(float* __restrict__ y, const float* __restrict__ gamma,
               const float* __restrict__ beta) {
    int row = blockIdx.x;
    int tid = threadIdx.x;
    float4 v4 = *(const float4*)&y[(size_t)row * 1024 + tid * 4];
    float v[4] = {v4.x, v4.y, v4.z, v4.w};
    float s = v[0] + v[1] + v[2] + v[3];
    float s2 = v[0]*v[0] + v[1]*v[1] + v[2]*v[2] + v[3]*v[3];
    #pragma unroll
    for (int off = 1; off < 64; off <<= 1) {
        s += __shfl_xor(s, off);
        s2 += __shfl_xor(s2, off);
    }
    __shared__ float red[8];
    int wave = tid >> 6, lane = tid & 63;
    if (lane == 0) { red[wave] = s; red[4 + wave] = s2; }
    __syncthreads();
    s = red[0] + red[1] + red[2] + red[3];
    s2 = red[4] + red[5] + red[6] + red[7];
    float mu = s * (1.f / 1024.f);
    float var = s2 * (1.f / 1024.f) - mu * mu;
    float rsq = rsqrtf(var + 1e-5f);
    float4 o4;
    float* o = (float*)&o4;
    #pragma unroll
    for (int e = 0; e < 4; e++) {
        int n = tid * 4 + e;
        o[e] = (v[e] - mu) * rsq * gamma[n] + beta[n];
    }
    *(float4*)&y[(size_t)row * 1024 + tid * 4] = o4;
}

extern "C" void kernel_launch(void* const* d_in, const int* in_sizes, int n_in,
                              void* d_out, int out_size, void* d_ws, size_t ws_size,
                              hipStream_t stream) {
    const float* x     = (const float*)d_in[0];
    const float* Wq    = (const float*)d_in[1];
    const float* bq    = (const float*)d_in[2];
    const float* Wk    = (const float*)d_in[3];
    const float* bk    = (const float*)d_in[4];
    const float* Wv    = (const float*)d_in[5];
    const float* bv    = (const float*)d_in[6];
    const float* Wg    = (const float*)d_in[7];
    const float* bg    = (const float*)d_in[8];
    const float* gamma = (const float*)d_in[9];
    const float* beta  = (const float*)d_in[10];
    float* out = (float*)d_out;   // reference output is fp32

    char* w = (char*)d_ws;
    const size_t MB = 1024 * 1024;
    short* xb  = (short*)(w + 0 * MB);    // [4096][1024] bf16
    short* Qb  = (short*)(w + 8 * MB);
    short* Kb  = (short*)(w + 16 * MB);
    short* Vb  = (short*)(w + 24 * MB);
    short* WT  = (short*)(w + 32 * MB);   // [3072][1024] bf16 (Wq^T|Wk^T|Wv^T)
    short* WgT = (short*)(w + 38 * MB);   // [1024][2048] bf16
    short* fb  = (short*)(w + 42 * MB);   // flowed bf16 [4096][1024]
    short* VT  = (short*)(w + 50 * MB);   // V^T per head [b*16+h][64 dv][2048 s] (8MB)

    cvt_kernel<<<4096, 256, 0, stream>>>(x, xb, 4096 * 1024 / 4);
    dim3 tb(32, 8);
    transpose_bf16<<<dim3(32, 32), tb, 0, stream>>>(Wq, WT, 1024, 1024);
    transpose_bf16<<<dim3(32, 32), tb, 0, stream>>>(Wk, WT + 1024 * 1024, 1024, 1024);
    transpose_bf16<<<dim3(32, 32), tb, 0, stream>>>(Wv, WT + 2 * 1024 * 1024, 1024, 1024);
    transpose_bf16<<<dim3(32, 64), tb, 0, stream>>>(Wg, WgT, 2048, 1024);
    gemm_qkv<<<dim3(32, 24), 256, 0, stream>>>(xb, WT, bq, bk, bv, Qb, Kb, Vb);
    vtrans_kernel<<<dim3(64, 2, 32), tb, 0, stream>>>(Vb, VT);
    attn_kernel<<<1024, 256, 0, stream>>>(Qb, Kb, VT, fb);
    gemm_gate<<<dim3(32, 8), 256, 0, stream>>>(xb, fb, WgT, bg, x, out);
    ln_kernel<<<4096, 256, 0, stream>>>(out, gamma, beta);
}

// Round 8
// 208.093 us; speedup vs baseline: 1.5157x; 1.1545x over previous
//
#include <hip/hip_runtime.h>
#include <hip/hip_bf16.h>

#define S_LEN 2048
#define NHEAD 16
#define HDIM 64
#define HID 1024

typedef __attribute__((ext_vector_type(8))) short bf16x8;
typedef __attribute__((ext_vector_type(4))) float f32x4;
typedef __attribute__((ext_vector_type(2))) unsigned int u32x2;

__device__ __forceinline__ unsigned short f2bf(float x) {
    unsigned int u = __builtin_bit_cast(unsigned int, x);
    u = (u + 0x7fffu + ((u >> 16) & 1u)) >> 16;
    return (unsigned short)u;
}
__device__ __forceinline__ float bf2f(unsigned short s) {
    unsigned int u = ((unsigned int)s) << 16;
    return __builtin_bit_cast(float, u);
}
__device__ __forceinline__ unsigned cvtpk_bf16(float lo, float hi) {
    unsigned r;
    asm("v_cvt_pk_bf16_f32 %0, %1, %2" : "=v"(r) : "v"(lo), "v"(hi));
    return r;
}
__device__ __forceinline__ void gload16(const short* g, short* l) {
    __builtin_amdgcn_global_load_lds(
        (const __attribute__((address_space(1))) unsigned int*)g,
        (__attribute__((address_space(3))) unsigned int*)l, 16, 0, 0);
}
__device__ __forceinline__ bf16x8 negbf8(bf16x8 v) {
    bf16x8 r;
    #pragma unroll
    for (int e = 0; e < 8; e++) r[e] = v[e] ^ (short)0x8000;
    return r;
}

// scale folded into Q: scores arrive as flow*log2(e) -> softmax via exp2
#define QSCALE 0.1803368801111168f   // 0.125 * log2(e)

// ---------------- prep: f32 -> bf16 convert (vectorized) ----------------
__global__ void cvt_kernel(const float* __restrict__ src, short* __restrict__ dst, int n4) {
    int i = blockIdx.x * blockDim.x + threadIdx.x;
    if (i < n4) {
        float4 v = reinterpret_cast<const float4*>(src)[i];
        short4 o;
        o.x = (short)f2bf(v.x); o.y = (short)f2bf(v.y);
        o.z = (short)f2bf(v.z); o.w = (short)f2bf(v.w);
        reinterpret_cast<short4*>(dst)[i] = o;
    }
}

// ------------- prep: tiled transpose f32 [R][C] -> bf16 [C][R] ----------
__global__ void transpose_bf16(const float* __restrict__ src, short* __restrict__ dst,
                               int R, int C) {
    __shared__ float tile[32][33];
    int bx = blockIdx.x * 32;
    int by = blockIdx.y * 32;
    int tx = threadIdx.x, ty = threadIdx.y;  // 32 x 8
    #pragma unroll
    for (int i = ty; i < 32; i += 8)
        tile[i][tx] = src[(size_t)(by + i) * C + bx + tx];
    __syncthreads();
    #pragma unroll
    for (int i = ty; i < 32; i += 8)
        dst[(size_t)(bx + i) * R + by + tx] = (short)f2bf(tile[tx][i]);
}

// ----- per-head V transpose: Vb[b*2048+s][h*64+dv] -> VT[(b*16+h)*64+dv][s]
__global__ void vtrans_kernel(const short* __restrict__ Vb, short* __restrict__ VT) {
    __shared__ short tile[32][34];
    int s0 = blockIdx.x * 32;
    int dv0 = blockIdx.y * 32;
    int bh = blockIdx.z;
    int b = bh >> 4, h = bh & 15;
    int tx = threadIdx.x, ty = threadIdx.y;  // 32 x 8
    #pragma unroll
    for (int i = ty; i < 32; i += 8)
        tile[i][tx] = Vb[(size_t)(b * S_LEN + s0 + i) * HID + h * HDIM + dv0 + tx];
    __syncthreads();
    #pragma unroll
    for (int i = ty; i < 32; i += 8)
        VT[(size_t)(bh * HDIM + dv0 + i) * S_LEN + s0 + tx] = tile[tx][i];
}

// ---------------- QKV GEMM: [4096,1024] @ [1024,3072] -------------------
// global_load_lds w=16 staging: linear [128][32] LDS, source-XOR swizzle,
// swizzled fragment reads (<=2-way banks = free). Q output pre-scaled.
__global__ __launch_bounds__(256, 2)
void gemm_qkv(const short* __restrict__ xb, const short* __restrict__ WT,
              const float* __restrict__ bq, const float* __restrict__ bk,
              const float* __restrict__ bv,
              short* __restrict__ Qb, short* __restrict__ Kb, short* __restrict__ Vb) {
    __shared__ short Al[128 * 32];
    __shared__ short Bl[128 * 32];
    int mb = blockIdx.x, nb = blockIdx.y;
    int tid = threadIdx.x;
    int wave = tid >> 6, lane = tid & 63;
    int wm = wave >> 1, wn = wave & 1;
    int lr = lane & 15, lg = lane >> 4;

    int r = tid >> 2;                 // staging row 0..63 (and +64)
    int c = tid & 3;
    int sc = (c ^ (r & 3)) * 8;       // source chunk (swizzled), same for r+64
    int dst0 = tid * 8;               // linear LDS dest (16B/lane)
    int dst1 = (tid + 256) * 8;
    const short* a0 = xb + (size_t)(mb * 128 + r) * 1024 + sc;
    const short* a1 = a0 + (size_t)64 * 1024;
    const short* b0 = WT + (size_t)(nb * 128 + r) * 1024 + sc;
    const short* b1 = b0 + (size_t)64 * 1024;
    int fsw = (lg ^ (lr & 3)) * 8;    // fragment-read swizzled chunk

    f32x4 acc[4][4] = {};

    for (int ks = 0; ks < 32; ++ks) {
        __syncthreads();
        gload16(a0 + ks * 32, &Al[dst0]);
        gload16(a1 + ks * 32, &Al[dst1]);
        gload16(b0 + ks * 32, &Bl[dst0]);
        gload16(b1 + ks * 32, &Bl[dst1]);
        __syncthreads();
        bf16x8 af[4], bfr[4];
        #pragma unroll
        for (int t = 0; t < 4; t++)
            af[t] = *(bf16x8*)&Al[(wm * 64 + t * 16 + lr) * 32 + fsw];
        #pragma unroll
        for (int t = 0; t < 4; t++)
            bfr[t] = *(bf16x8*)&Bl[(wn * 64 + t * 16 + lr) * 32 + fsw];
        #pragma unroll
        for (int i = 0; i < 4; i++)
            #pragma unroll
            for (int jn = 0; jn < 4; jn++)
                acc[i][jn] = __builtin_amdgcn_mfma_f32_16x16x32_bf16(af[i], bfr[jn], acc[i][jn], 0, 0, 0);
    }

    #pragma unroll
    for (int jn = 0; jn < 4; jn++) {
        int n = nb * 128 + wn * 64 + jn * 16 + lr;
        int which = n >> 10;
        int n1 = n & 1023;
        const float* bias = (which == 0) ? bq : (which == 1) ? bk : bv;
        short* out = (which == 0) ? Qb : (which == 1) ? Kb : Vb;
        float scale = (which == 0) ? QSCALE : 1.0f;
        float bv_ = bias[n1];
        #pragma unroll
        for (int i = 0; i < 4; i++) {
            #pragma unroll
            for (int j = 0; j < 4; j++) {
                int mm = mb * 128 + wm * 64 + i * 16 + lg * 4 + j;
                out[(size_t)mm * 1024 + n1] = (short)f2bf((acc[i][jn][j] + bv_) * scale);
            }
        }
    }
}

// ---------------- flash attention with antisymmetric flow ---------------
// scores pre-scaled to log2 domain (Q folded); Qt staged NEGATED so
// S = mfma(kf,Qf, mfma(-qf,Kf,S)) needs no VALU subtract; softmax = exp2;
// P packed via v_cvt_pk_bf16_f32. T2 XOR swizzle throughout.
__global__ __launch_bounds__(256, 4)
void attn_kernel(const short* __restrict__ Qb, const short* __restrict__ Kb,
                 const short* __restrict__ VT, short* __restrict__ Fb) {
    __shared__ short Kt[64 * 64];
    __shared__ short Qt[64 * 64];          // holds -Q rows
    __shared__ short Vt[64 * 64];
    __shared__ short Pl[4][16 * 64];

    int bid = blockIdx.x;
    int qb = bid & 31;
    int bh = bid >> 5;
    int b = bh >> 4, h = bh & 15;
    int tid = threadIdx.x;
    int wave = tid >> 6, lane = tid & 63;
    int lr = lane & 15, lg = lane >> 4;

    // hoisted per-wave Q/K fragments (B-side), rows = wave's 16 q-rows
    size_t rowbase = ((size_t)(b * S_LEN + qb * 64 + wave * 16 + lr)) * HID + h * HDIM;
    bf16x8 Qf[2], Kf[2];
    #pragma unroll
    for (int cc = 0; cc < 2; cc++) {
        Qf[cc] = *(const bf16x8*)(Qb + rowbase + cc * 32 + lg * 8);
        Kf[cc] = *(const bf16x8*)(Kb + rowbase + cc * 32 + lg * 8);
    }

    // hoisted staging addresses: thread owns rows r0, r0+32, chunk c
    int r0 = tid >> 3;
    int c = tid & 7;
    int swz = (c ^ (r0 & 7)) * 8;          // same for r0+32
    int dst0 = r0 * 64 + swz;
    int dst1 = (r0 + 32) * 64 + swz;
    const short* kp = Kb + (size_t)(b * S_LEN + r0) * HID + h * HDIM + c * 8;
    const short* qp = Qb + (size_t)(b * S_LEN + r0) * HID + h * HDIM + c * 8;
    const short* vp = VT + (size_t)bh * HDIM * S_LEN + (size_t)r0 * S_LEN + c * 8;

    f32x4 O[4] = {};
    float m = -1e30f, l = 0.f;   // per-lane softmax state (log2 domain), q = lr

    for (int kt = 0; kt < 32; ++kt) {
        __syncthreads();
        *(bf16x8*)&Kt[dst0] = *(const bf16x8*)kp;
        *(bf16x8*)&Kt[dst1] = *(const bf16x8*)(kp + 32 * HID);
        *(bf16x8*)&Qt[dst0] = negbf8(*(const bf16x8*)qp);
        *(bf16x8*)&Qt[dst1] = negbf8(*(const bf16x8*)(qp + 32 * HID));
        *(bf16x8*)&Vt[dst0] = *(const bf16x8*)vp;
        *(bf16x8*)&Vt[dst1] = *(const bf16x8*)(vp + 32 * S_LEN);
        kp += 64 * HID; qp += 64 * HID; vp += 64;
        __syncthreads();

        // S^T = (QK^T - KQ^T)*0.125*log2e, lane holds q=lr, k=16t+4lg+j
        f32x4 S[4] = {};
        __builtin_amdgcn_s_setprio(1);
        #pragma unroll
        for (int t = 0; t < 4; t++) {
            #pragma unroll
            for (int c2 = 0; c2 < 2; c2++) {
                int fo = (t * 16 + lr) * 64 + (((4 * c2 + lg) ^ (lr & 7)) * 8);
                bf16x8 kf = *(bf16x8*)&Kt[fo];
                bf16x8 nqf = *(bf16x8*)&Qt[fo];
                S[t] = __builtin_amdgcn_mfma_f32_16x16x32_bf16(kf, Qf[c2], S[t], 0, 0, 0);
                S[t] = __builtin_amdgcn_mfma_f32_16x16x32_bf16(nqf, Kf[c2], S[t], 0, 0, 0);
            }
        }
        __builtin_amdgcn_s_setprio(0);

        float pm = -1e30f;
        #pragma unroll
        for (int t = 0; t < 4; t++)
            #pragma unroll
            for (int j = 0; j < 4; j++) pm = fmaxf(pm, S[t][j]);
        pm = fmaxf(pm, __shfl_xor(pm, 16));
        pm = fmaxf(pm, __shfl_xor(pm, 32));

        // defer-max (T13)
        if (__any(pm > m + 8.f)) {
            float mn = fmaxf(m, pm);
            float alpha = exp2f(m - mn);
            m = mn;
            l *= alpha;
            float a[4];
            #pragma unroll
            for (int j = 0; j < 4; j++) a[j] = __shfl(alpha, lg * 4 + j);
            #pragma unroll
            for (int dvt = 0; dvt < 4; dvt++)
                #pragma unroll
                for (int j = 0; j < 4; j++) O[dvt][j] *= a[j];
        }

        float rs = 0.f;
        #pragma unroll
        for (int t = 0; t < 4; t++) {
            float p0 = exp2f(S[t][0] - m);
            float p1 = exp2f(S[t][1] - m);
            float p2 = exp2f(S[t][2] - m);
            float p3 = exp2f(S[t][3] - m);
            rs += (p0 + p1) + (p2 + p3);
            u32x2 pw;
            pw[0] = cvtpk_bf16(p0, p1);
            pw[1] = cvtpk_bf16(p2, p3);
            int po = lr * 64 + (((2 * t + (lg >> 1)) ^ (lr & 7)) * 8) + (lg & 1) * 4;
            *(u32x2*)&Pl[wave][po] = pw;
        }
        rs += __shfl_xor(rs, 16);
        rs += __shfl_xor(rs, 32);
        l += rs;

        // PV
        __builtin_amdgcn_s_setprio(1);
        #pragma unroll
        for (int c2 = 0; c2 < 2; c2++) {
            bf16x8 pf = *(bf16x8*)&Pl[wave][lr * 64 + (((4 * c2 + lg) ^ (lr & 7)) * 8)];
            #pragma unroll
            for (int dvt = 0; dvt < 4; dvt++) {
                bf16x8 vf = *(bf16x8*)&Vt[(dvt * 16 + lr) * 64 + (((4 * c2 + lg) ^ (lr & 7)) * 8)];
                O[dvt] = __builtin_amdgcn_mfma_f32_16x16x32_bf16(pf, vf, O[dvt], 0, 0, 0);
            }
        }
        __builtin_amdgcn_s_setprio(0);
    }

    float linv = 1.f / l;
    float li[4];
    #pragma unroll
    for (int j = 0; j < 4; j++) li[j] = __shfl(linv, lg * 4 + j);
    #pragma unroll
    for (int dvt = 0; dvt < 4; dvt++) {
        #pragma unroll
        for (int j = 0; j < 4; j++) {
            int q = qb * 64 + wave * 16 + lg * 4 + j;
            int dv = dvt * 16 + lr;
            Fb[((size_t)(b * S_LEN + q)) * HID + h * HDIM + dv] =
                (short)f2bf(O[dvt][j] * li[j]);
        }
    }
}

// ------- gate GEMM (K=2048 over [xb | flowed]) + sigmoid + residual -----
__global__ __launch_bounds__(256, 2)
void gemm_gate(const short* __restrict__ xb, const short* __restrict__ fb,
               const short* __restrict__ WgT, const float* __restrict__ bg,
               const float* __restrict__ x, float* __restrict__ y) {
    __shared__ short Al[128 * 32];
    __shared__ short Bl[128 * 32];
    int mb = blockIdx.x, nb = blockIdx.y;
    int tid = threadIdx.x;
    int wave = tid >> 6, lane = tid & 63;
    int wm = wave >> 1, wn = wave & 1;
    int lr = lane & 15, lg = lane >> 4;

    int r = tid >> 2;
    int c = tid & 3;
    int sc = (c ^ (r & 3)) * 8;
    int dst0 = tid * 8;
    int dst1 = (tid + 256) * 8;
    size_t arow0 = (size_t)(mb * 128 + r) * 1024 + sc;
    size_t arow1 = arow0 + (size_t)64 * 1024;
    const short* b0 = WgT + (size_t)(nb * 128 + r) * 2048 + sc;
    const short* b1 = b0 + (size_t)64 * 2048;
    int fsw = (lg ^ (lr & 3)) * 8;

    f32x4 acc[4][4] = {};

    for (int ks = 0; ks < 64; ++ks) {
        int kg = ks * 32;
        const short* A = (kg < 1024) ? (xb + kg) : (fb + (kg - 1024));
        __syncthreads();
        gload16(A + arow0, &Al[dst0]);
        gload16(A + arow1, &Al[dst1]);
        gload16(b0 + kg, &Bl[dst0]);
        gload16(b1 + kg, &Bl[dst1]);
        __syncthreads();
        bf16x8 af[4], bfr[4];
        #pragma unroll
        for (int t = 0; t < 4; t++)
            af[t] = *(bf16x8*)&Al[(wm * 64 + t * 16 + lr) * 32 + fsw];
        #pragma unroll
        for (int t = 0; t < 4; t++)
            bfr[t] = *(bf16x8*)&Bl[(wn * 64 + t * 16 + lr) * 32 + fsw];
        #pragma unroll
        for (int i = 0; i < 4; i++)
            #pragma unroll
            for (int jn = 0; jn < 4; jn++)
                acc[i][jn] = __builtin_amdgcn_mfma_f32_16x16x32_bf16(af[i], bfr[jn], acc[i][jn], 0, 0, 0);
    }

    #pragma unroll
    for (int jn = 0; jn < 4; jn++) {
        int n = nb * 128 + wn * 64 + jn * 16 + lr;
        float bgv = bg[n];
        #pragma unroll
        for (int i = 0; i < 4; i++) {
            #pragma unroll
            for (int j = 0; j < 4; j++) {
                int mm = mb * 128 + wm * 64 + i * 16 + lg * 4 + j;
                size_t idx = (size_t)mm * 1024 + n;
                float z = acc[i][jn][j] + bgv;
                float gate = 1.f / (1.f + __expf(-z));
                float fv = bf2f((unsigned short)fb[idx]);
                y[idx] = x[idx] + gate * fv;
            }
        }
    }
}

// ---------------- row LayerNorm in place (fp32 -> fp32) ----------------
__global__ __launch_bounds__(256)
void ln_kernel(float* __restrict__ y, const float* __restrict__ gamma,
               const float* __restrict__ beta) {
    int row = blockIdx.x;
    int tid = threadIdx.x;
    float4 v4 = *(const float4*)&y[(size_t)row * 1024 + tid * 4];
    float v[4] = {v4.x, v4.y, v4.z, v4.w};
    float s = v[0] + v[1] + v[2] + v[3];
    float s2 = v[0]*v[0] + v[1]*v[1] + v[2]*v[2] + v[3]*v[3];
    #pragma unroll
    for (int off = 1; off < 64; off <<= 1) {
        s += __shfl_xor(s, off);
        s2 += __shfl_xor(s2, off);
    }
    __shared__ float red[8];
    int wave = tid >> 6, lane = tid & 63;
    if (lane == 0) { red[wave] = s; red[4 + wave] = s2; }
    __syncthreads();
    s = red[0] + red[1] + red[2] + red[3];
    s2 = red[4] + red[5] + red[6] + red[7];
    float mu = s * (1.f / 1024.f);
    float var = s2 * (1.f / 1024.f) - mu * mu;
    float rsq = rsqrtf(var + 1e-5f);
    float4 o4;
    float* o = (float*)&o4;
    #pragma unroll
    for (int e = 0; e < 4; e++) {
        int n = tid * 4 + e;
        o[e] = (v[e] - mu) * rsq * gamma[n] + beta[n];
    }
    *(float4*)&y[(size_t)row * 1024 + tid * 4] = o4;
}

extern "C" void kernel_launch(void* const* d_in, const int* in_sizes, int n_in,
                              void* d_out, int out_size, void* d_ws, size_t ws_size,
                              hipStream_t stream) {
    const float* x     = (const float*)d_in[0];
    const float* Wq    = (const float*)d_in[1];
    const float* bq    = (const float*)d_in[2];
    const float* Wk    = (const float*)d_in[3];
    const float* bk    = (const float*)d_in[4];
    const float* Wv    = (const float*)d_in[5];
    const float* bv    = (const float*)d_in[6];
    const float* Wg    = (const float*)d_in[7];
    const float* bg    = (const float*)d_in[8];
    const float* gamma = (const float*)d_in[9];
    const float* beta  = (const float*)d_in[10];
    float* out = (float*)d_out;   // reference output is fp32

    char* w = (char*)d_ws;
    const size_t MB = 1024 * 1024;
    short* xb  = (short*)(w + 0 * MB);    // [4096][1024] bf16
    short* Qb  = (short*)(w + 8 * MB);    // pre-scaled by QSCALE
    short* Kb  = (short*)(w + 16 * MB);
    short* Vb  = (short*)(w + 24 * MB);
    short* WT  = (short*)(w + 32 * MB);   // [3072][1024] bf16 (Wq^T|Wk^T|Wv^T)
    short* WgT = (short*)(w + 38 * MB);   // [1024][2048] bf16
    short* fb  = (short*)(w + 42 * MB);   // flowed bf16 [4096][1024]
    short* VT  = (short*)(w + 50 * MB);   // V^T per head [b*16+h][64 dv][2048 s]

    cvt_kernel<<<4096, 256, 0, stream>>>(x, xb, 4096 * 1024 / 4);
    dim3 tb(32, 8);
    transpose_bf16<<<dim3(32, 32), tb, 0, stream>>>(Wq, WT, 1024, 1024);
    transpose_bf16<<<dim3(32, 32), tb, 0, stream>>>(Wk, WT + 1024 * 1024, 1024, 1024);
    transpose_bf16<<<dim3(32, 32), tb, 0, stream>>>(Wv, WT + 2 * 1024 * 1024, 1024, 1024);
    transpose_bf16<<<dim3(32, 64), tb, 0, stream>>>(Wg, WgT, 2048, 1024);
    gemm_qkv<<<dim3(32, 24), 256, 0, stream>>>(xb, WT, bq, bk, bv, Qb, Kb, Vb);
    vtrans_kernel<<<dim3(64, 2, 32), tb, 0, stream>>>(Vb, VT);
    attn_kernel<<<1024, 256, 0, stream>>>(Qb, Kb, VT, fb);
    gemm_gate<<<dim3(32, 8), 256, 0, stream>>>(xb, fb, WgT, bg, x, out);
    ln_kernel<<<4096, 256, 0, stream>>>(out, gamma, beta);
}

// Round 9
// 204.927 us; speedup vs baseline: 1.5391x; 1.0155x over previous
//
#include <hip/hip_runtime.h>
#include <hip/hip_bf16.h>

#define S_LEN 2048
#define NHEAD 16
#define HDIM 64
#define HID 1024

typedef __attribute__((ext_vector_type(8))) short bf16x8;
typedef __attribute__((ext_vector_type(4))) float f32x4;
typedef __attribute__((ext_vector_type(4))) unsigned int u32x4;
typedef __attribute__((ext_vector_type(2))) unsigned int u32x2;

__device__ __forceinline__ unsigned short f2bf(float x) {
    unsigned int u = __builtin_bit_cast(unsigned int, x);
    u = (u + 0x7fffu + ((u >> 16) & 1u)) >> 16;
    return (unsigned short)u;
}
__device__ __forceinline__ float bf2f(unsigned short s) {
    unsigned int u = ((unsigned int)s) << 16;
    return __builtin_bit_cast(float, u);
}
__device__ __forceinline__ unsigned cvtpk_bf16(float lo, float hi) {
    unsigned r;
    asm("v_cvt_pk_bf16_f32 %0, %1, %2" : "=v"(r) : "v"(lo), "v"(hi));
    return r;
}
__device__ __forceinline__ void gload16(const short* g, short* l) {
    __builtin_amdgcn_global_load_lds(
        (const __attribute__((address_space(1))) unsigned int*)g,
        (__attribute__((address_space(3))) unsigned int*)l, 16, 0, 0);
}
__device__ __forceinline__ bf16x8 negbf8(bf16x8 v) {
    u32x4 u = __builtin_bit_cast(u32x4, v);
    #pragma unroll
    for (int e = 0; e < 4; e++) u[e] ^= 0x80008000u;
    return __builtin_bit_cast(bf16x8, u);
}

// scale folded into Q: scores arrive as flow*log2(e) -> softmax via exp2
#define QSCALE 0.1803368801111168f   // 0.125 * log2(e)

// ---------------- prep: f32 -> bf16 convert (vectorized) ----------------
__global__ void cvt_kernel(const float* __restrict__ src, short* __restrict__ dst, int n4) {
    int i = blockIdx.x * blockDim.x + threadIdx.x;
    if (i < n4) {
        float4 v = reinterpret_cast<const float4*>(src)[i];
        short4 o;
        o.x = (short)f2bf(v.x); o.y = (short)f2bf(v.y);
        o.z = (short)f2bf(v.z); o.w = (short)f2bf(v.w);
        reinterpret_cast<short4*>(dst)[i] = o;
    }
}

// ------------- prep: tiled transpose f32 [R][C] -> bf16 [C][R] ----------
__global__ void transpose_bf16(const float* __restrict__ src, short* __restrict__ dst,
                               int R, int C) {
    __shared__ float tile[32][33];
    int bx = blockIdx.x * 32;
    int by = blockIdx.y * 32;
    int tx = threadIdx.x, ty = threadIdx.y;  // 32 x 8
    #pragma unroll
    for (int i = ty; i < 32; i += 8)
        tile[i][tx] = src[(size_t)(by + i) * C + bx + tx];
    __syncthreads();
    #pragma unroll
    for (int i = ty; i < 32; i += 8)
        dst[(size_t)(bx + i) * R + by + tx] = (short)f2bf(tile[tx][i]);
}

// ----- per-head V transpose: Vb[b*2048+s][h*64+dv] -> VT[(b*16+h)*64+dv][s]
__global__ void vtrans_kernel(const short* __restrict__ Vb, short* __restrict__ VT) {
    __shared__ short tile[32][34];
    int s0 = blockIdx.x * 32;
    int dv0 = blockIdx.y * 32;
    int bh = blockIdx.z;
    int b = bh >> 4, h = bh & 15;
    int tx = threadIdx.x, ty = threadIdx.y;  // 32 x 8
    #pragma unroll
    for (int i = ty; i < 32; i += 8)
        tile[i][tx] = Vb[(size_t)(b * S_LEN + s0 + i) * HID + h * HDIM + dv0 + tx];
    __syncthreads();
    #pragma unroll
    for (int i = ty; i < 32; i += 8)
        VT[(size_t)(bh * HDIM + dv0 + i) * S_LEN + s0 + tx] = tile[tx][i];
}

// ---------------- QKV GEMM: [4096,1024] @ [1024,3072] -------------------
// global_load_lds w=16 staging: linear [128][32] LDS, source-XOR swizzle,
// swizzled fragment reads (<=2-way banks = free). Q output pre-scaled.
__global__ __launch_bounds__(256, 2)
void gemm_qkv(const short* __restrict__ xb, const short* __restrict__ WT,
              const float* __restrict__ bq, const float* __restrict__ bk,
              const float* __restrict__ bv,
              short* __restrict__ Qb, short* __restrict__ Kb, short* __restrict__ Vb) {
    __shared__ short Al[128 * 32];
    __shared__ short Bl[128 * 32];
    int mb = blockIdx.x, nb = blockIdx.y;
    int tid = threadIdx.x;
    int wave = tid >> 6, lane = tid & 63;
    int wm = wave >> 1, wn = wave & 1;
    int lr = lane & 15, lg = lane >> 4;

    int r = tid >> 2;                 // staging row 0..63 (and +64)
    int c = tid & 3;
    int sc = (c ^ (r & 3)) * 8;       // source chunk (swizzled), same for r+64
    int dst0 = tid * 8;               // linear LDS dest (16B/lane)
    int dst1 = (tid + 256) * 8;
    const short* a0 = xb + (size_t)(mb * 128 + r) * 1024 + sc;
    const short* a1 = a0 + (size_t)64 * 1024;
    const short* b0 = WT + (size_t)(nb * 128 + r) * 1024 + sc;
    const short* b1 = b0 + (size_t)64 * 1024;
    int fsw = (lg ^ (lr & 3)) * 8;    // fragment-read swizzled chunk

    f32x4 acc[4][4] = {};

    for (int ks = 0; ks < 32; ++ks) {
        __syncthreads();
        gload16(a0 + ks * 32, &Al[dst0]);
        gload16(a1 + ks * 32, &Al[dst1]);
        gload16(b0 + ks * 32, &Bl[dst0]);
        gload16(b1 + ks * 32, &Bl[dst1]);
        __syncthreads();
        bf16x8 af[4], bfr[4];
        #pragma unroll
        for (int t = 0; t < 4; t++)
            af[t] = *(bf16x8*)&Al[(wm * 64 + t * 16 + lr) * 32 + fsw];
        #pragma unroll
        for (int t = 0; t < 4; t++)
            bfr[t] = *(bf16x8*)&Bl[(wn * 64 + t * 16 + lr) * 32 + fsw];
        #pragma unroll
        for (int i = 0; i < 4; i++)
            #pragma unroll
            for (int jn = 0; jn < 4; jn++)
                acc[i][jn] = __builtin_amdgcn_mfma_f32_16x16x32_bf16(af[i], bfr[jn], acc[i][jn], 0, 0, 0);
    }

    #pragma unroll
    for (int jn = 0; jn < 4; jn++) {
        int n = nb * 128 + wn * 64 + jn * 16 + lr;
        int which = n >> 10;
        int n1 = n & 1023;
        const float* bias = (which == 0) ? bq : (which == 1) ? bk : bv;
        short* out = (which == 0) ? Qb : (which == 1) ? Kb : Vb;
        float scale = (which == 0) ? QSCALE : 1.0f;
        float bv_ = bias[n1];
        #pragma unroll
        for (int i = 0; i < 4; i++) {
            #pragma unroll
            for (int j = 0; j < 4; j++) {
                int mm = mb * 128 + wm * 64 + i * 16 + lg * 4 + j;
                out[(size_t)mm * 1024 + n1] = (short)f2bf((acc[i][jn][j] + bv_) * scale);
            }
        }
    }
}

// ---------------- flash attention with antisymmetric flow ---------------
// log2-domain scores (Q pre-scaled); Qt staged NEGATED so S = chained MFMA;
// T2 XOR swizzle; T14 async-STAGE: tile t+1's global loads issue right after
// the write barrier and complete under tile t's compute.
__global__ __launch_bounds__(256, 4)
void attn_kernel(const short* __restrict__ Qb, const short* __restrict__ Kb,
                 const short* __restrict__ VT, short* __restrict__ Fb) {
    __shared__ short Kt[64 * 64];
    __shared__ short Qt[64 * 64];          // holds -Q rows
    __shared__ short Vt[64 * 64];
    __shared__ short Pl[4][16 * 64];

    int bid = blockIdx.x;
    int qb = bid & 31;
    int bh = bid >> 5;
    int b = bh >> 4, h = bh & 15;
    int tid = threadIdx.x;
    int wave = tid >> 6, lane = tid & 63;
    int lr = lane & 15, lg = lane >> 4;

    // hoisted per-wave Q/K fragments (B-side), rows = wave's 16 q-rows
    size_t rowbase = ((size_t)(b * S_LEN + qb * 64 + wave * 16 + lr)) * HID + h * HDIM;
    bf16x8 Qf[2], Kf[2];
    #pragma unroll
    for (int cc = 0; cc < 2; cc++) {
        Qf[cc] = *(const bf16x8*)(Qb + rowbase + cc * 32 + lg * 8);
        Kf[cc] = *(const bf16x8*)(Kb + rowbase + cc * 32 + lg * 8);
    }

    // staging addresses: thread owns rows r0, r0+32, chunk c
    int r0 = tid >> 3;
    int c = tid & 7;
    int swz = (c ^ (r0 & 7)) * 8;          // same for r0+32
    int dst0 = r0 * 64 + swz;
    int dst1 = (r0 + 32) * 64 + swz;
    const short* kp = Kb + (size_t)(b * S_LEN + r0) * HID + h * HDIM + c * 8;
    const short* qp = Qb + (size_t)(b * S_LEN + r0) * HID + h * HDIM + c * 8;
    const short* vp = VT + (size_t)bh * HDIM * S_LEN + (size_t)r0 * S_LEN + c * 8;

    // prologue: prefetch tile 0 into registers
    bf16x8 kv0 = *(const bf16x8*)kp;
    bf16x8 kv1 = *(const bf16x8*)(kp + 32 * HID);
    bf16x8 qv0 = *(const bf16x8*)qp;
    bf16x8 qv1 = *(const bf16x8*)(qp + 32 * HID);
    bf16x8 vv0 = *(const bf16x8*)vp;
    bf16x8 vv1 = *(const bf16x8*)(vp + 32 * S_LEN);
    kp += 64 * HID; qp += 64 * HID; vp += 64;

    f32x4 O[4] = {};
    float m = -1e30f, l = 0.f;   // per-lane softmax state (log2 domain), q = lr

    for (int kt = 0; kt < 32; ++kt) {
        __syncthreads();                       // prev tile's readers done
        *(bf16x8*)&Kt[dst0] = kv0;
        *(bf16x8*)&Kt[dst1] = kv1;
        *(bf16x8*)&Qt[dst0] = negbf8(qv0);
        *(bf16x8*)&Qt[dst1] = negbf8(qv1);
        *(bf16x8*)&Vt[dst0] = vv0;
        *(bf16x8*)&Vt[dst1] = vv1;
        __syncthreads();                       // tile visible

        if (kt < 31) {                         // issue next-tile loads EARLY (T14)
            kv0 = *(const bf16x8*)kp;
            kv1 = *(const bf16x8*)(kp + 32 * HID);
            qv0 = *(const bf16x8*)qp;
            qv1 = *(const bf16x8*)(qp + 32 * HID);
            vv0 = *(const bf16x8*)vp;
            vv1 = *(const bf16x8*)(vp + 32 * S_LEN);
            kp += 64 * HID; qp += 64 * HID; vp += 64;
        }

        // S^T = (QK^T - KQ^T)*0.125*log2e, lane holds q=lr, k=16t+4lg+j
        f32x4 S[4] = {};
        __builtin_amdgcn_s_setprio(1);
        #pragma unroll
        for (int t = 0; t < 4; t++) {
            #pragma unroll
            for (int c2 = 0; c2 < 2; c2++) {
                int fo = (t * 16 + lr) * 64 + (((4 * c2 + lg) ^ (lr & 7)) * 8);
                bf16x8 kf = *(bf16x8*)&Kt[fo];
                bf16x8 nqf = *(bf16x8*)&Qt[fo];
                S[t] = __builtin_amdgcn_mfma_f32_16x16x32_bf16(kf, Qf[c2], S[t], 0, 0, 0);
                S[t] = __builtin_amdgcn_mfma_f32_16x16x32_bf16(nqf, Kf[c2], S[t], 0, 0, 0);
            }
        }
        __builtin_amdgcn_s_setprio(0);

        float pm = -1e30f;
        #pragma unroll
        for (int t = 0; t < 4; t++)
            #pragma unroll
            for (int j = 0; j < 4; j++) pm = fmaxf(pm, S[t][j]);
        pm = fmaxf(pm, __shfl_xor(pm, 16));
        pm = fmaxf(pm, __shfl_xor(pm, 32));

        // defer-max (T13)
        if (__any(pm > m + 8.f)) {
            float mn = fmaxf(m, pm);
            float alpha = exp2f(m - mn);
            m = mn;
            l *= alpha;
            float a[4];
            #pragma unroll
            for (int j = 0; j < 4; j++) a[j] = __shfl(alpha, lg * 4 + j);
            #pragma unroll
            for (int dvt = 0; dvt < 4; dvt++)
                #pragma unroll
                for (int j = 0; j < 4; j++) O[dvt][j] *= a[j];
        }

        float rs = 0.f;
        #pragma unroll
        for (int t = 0; t < 4; t++) {
            float p0 = exp2f(S[t][0] - m);
            float p1 = exp2f(S[t][1] - m);
            float p2 = exp2f(S[t][2] - m);
            float p3 = exp2f(S[t][3] - m);
            rs += (p0 + p1) + (p2 + p3);
            u32x2 pw;
            pw[0] = cvtpk_bf16(p0, p1);
            pw[1] = cvtpk_bf16(p2, p3);
            int po = lr * 64 + (((2 * t + (lg >> 1)) ^ (lr & 7)) * 8) + (lg & 1) * 4;
            *(u32x2*)&Pl[wave][po] = pw;
        }
        rs += __shfl_xor(rs, 16);
        rs += __shfl_xor(rs, 32);
        l += rs;

        // PV
        __builtin_amdgcn_s_setprio(1);
        #pragma unroll
        for (int c2 = 0; c2 < 2; c2++) {
            bf16x8 pf = *(bf16x8*)&Pl[wave][lr * 64 + (((4 * c2 + lg) ^ (lr & 7)) * 8)];
            #pragma unroll
            for (int dvt = 0; dvt < 4; dvt++) {
                bf16x8 vf = *(bf16x8*)&Vt[(dvt * 16 + lr) * 64 + (((4 * c2 + lg) ^ (lr & 7)) * 8)];
                O[dvt] = __builtin_amdgcn_mfma_f32_16x16x32_bf16(pf, vf, O[dvt], 0, 0, 0);
            }
        }
        __builtin_amdgcn_s_setprio(0);
    }

    float linv = 1.f / l;
    float li[4];
    #pragma unroll
    for (int j = 0; j < 4; j++) li[j] = __shfl(linv, lg * 4 + j);
    #pragma unroll
    for (int dvt = 0; dvt < 4; dvt++) {
        #pragma unroll
        for (int j = 0; j < 4; j++) {
            int q = qb * 64 + wave * 16 + lg * 4 + j;
            int dv = dvt * 16 + lr;
            Fb[((size_t)(b * S_LEN + q)) * HID + h * HDIM + dv] =
                (short)f2bf(O[dvt][j] * li[j]);
        }
    }
}

// ------- gate GEMM (K=2048 over [xb | flowed]) + sigmoid + residual -----
__global__ __launch_bounds__(256, 2)
void gemm_gate(const short* __restrict__ xb, const short* __restrict__ fb,
               const short* __restrict__ WgT, const float* __restrict__ bg,
               const float* __restrict__ x, float* __restrict__ y) {
    __shared__ short Al[128 * 32];
    __shared__ short Bl[128 * 32];
    int mb = blockIdx.x, nb = blockIdx.y;
    int tid = threadIdx.x;
    int wave = tid >> 6, lane = tid & 63;
    int wm = wave >> 1, wn = wave & 1;
    int lr = lane & 15, lg = lane >> 4;

    int r = tid >> 2;
    int c = tid & 3;
    int sc = (c ^ (r & 3)) * 8;
    int dst0 = tid * 8;
    int dst1 = (tid + 256) * 8;
    size_t arow0 = (size_t)(mb * 128 + r) * 1024 + sc;
    size_t arow1 = arow0 + (size_t)64 * 1024;
    const short* b0 = WgT + (size_t)(nb * 128 + r) * 2048 + sc;
    const short* b1 = b0 + (size_t)64 * 2048;
    int fsw = (lg ^ (lr & 3)) * 8;

    f32x4 acc[4][4] = {};

    for (int ks = 0; ks < 64; ++ks) {
        int kg = ks * 32;
        const short* A = (kg < 1024) ? (xb + kg) : (fb + (kg - 1024));
        __syncthreads();
        gload16(A + arow0, &Al[dst0]);
        gload16(A + arow1, &Al[dst1]);
        gload16(b0 + kg, &Bl[dst0]);
        gload16(b1 + kg, &Bl[dst1]);
        __syncthreads();
        bf16x8 af[4], bfr[4];
        #pragma unroll
        for (int t = 0; t < 4; t++)
            af[t] = *(bf16x8*)&Al[(wm * 64 + t * 16 + lr) * 32 + fsw];
        #pragma unroll
        for (int t = 0; t < 4; t++)
            bfr[t] = *(bf16x8*)&Bl[(wn * 64 + t * 16 + lr) * 32 + fsw];
        #pragma unroll
        for (int i = 0; i < 4; i++)
            #pragma unroll
            for (int jn = 0; jn < 4; jn++)
                acc[i][jn] = __builtin_amdgcn_mfma_f32_16x16x32_bf16(af[i], bfr[jn], acc[i][jn], 0, 0, 0);
    }

    #pragma unroll
    for (int jn = 0; jn < 4; jn++) {
        int n = nb * 128 + wn * 64 + jn * 16 + lr;
        float bgv = bg[n];
        #pragma unroll
        for (int i = 0; i < 4; i++) {
            #pragma unroll
            for (int j = 0; j < 4; j++) {
                int mm = mb * 128 + wm * 64 + i * 16 + lg * 4 + j;
                size_t idx = (size_t)mm * 1024 + n;
                float z = acc[i][jn][j] + bgv;
                float gate = 1.f / (1.f + __expf(-z));
                float fv = bf2f((unsigned short)fb[idx]);
                y[idx] = x[idx] + gate * fv;
            }
        }
    }
}

// ---------------- row LayerNorm in place (fp32 -> fp32) ----------------
__global__ __launch_bounds__(256)
void ln_kernel(float* __restrict__ y, const float* __restrict__ gamma,
               const float* __restrict__ beta) {
    int row = blockIdx.x;
    int tid = threadIdx.x;
    float4 v4 = *(const float4*)&y[(size_t)row * 1024 + tid * 4];
    float v[4] = {v4.x, v4.y, v4.z, v4.w};
    float s = v[0] + v[1] + v[2] + v[3];
    float s2 = v[0]*v[0] + v[1]*v[1] + v[2]*v[2] + v[3]*v[3];
    #pragma unroll
    for (int off = 1; off < 64; off <<= 1) {
        s += __shfl_xor(s, off);
        s2 += __shfl_xor(s2, off);
    }
    __shared__ float red[8];
    int wave = tid >> 6, lane = tid & 63;
    if (lane == 0) { red[wave] = s; red[4 + wave] = s2; }
    __syncthreads();
    s = red[0] + red[1] + red[2] + red[3];
    s2 = red[4] + red[5] + red[6] + red[7];
    float mu = s * (1.f / 1024.f);
    float var = s2 * (1.f / 1024.f) - mu * mu;
    float rsq = rsqrtf(var + 1e-5f);
    float4 o4;
    float* o = (float*)&o4;
    #pragma unroll
    for (int e = 0; e < 4; e++) {
        int n = tid * 4 + e;
        o[e] = (v[e] - mu) * rsq * gamma[n] + beta[n];
    }
    *(float4*)&y[(size_t)row * 1024 + tid * 4] = o4;
}

extern "C" void kernel_launch(void* const* d_in, const int* in_sizes, int n_in,
                              void* d_out, int out_size, void* d_ws, size_t ws_size,
                              hipStream_t stream) {
    const float* x     = (const float*)d_in[0];
    const float* Wq    = (const float*)d_in[1];
    const float* bq    = (const float*)d_in[2];
    const float* Wk    = (const float*)d_in[3];
    const float* bk    = (const float*)d_in[4];
    const float* Wv    = (const float*)d_in[5];
    const float* bv    = (const float*)d_in[6];
    const float* Wg    = (const float*)d_in[7];
    const float* bg    = (const float*)d_in[8];
    const float* gamma = (const float*)d_in[9];
    const float* beta  = (const float*)d_in[10];
    float* out = (float*)d_out;   // reference output is fp32

    char* w = (char*)d_ws;
    const size_t MB = 1024 * 1024;
    short* xb  = (short*)(w + 0 * MB);    // [4096][1024] bf16
    short* Qb  = (short*)(w + 8 * MB);    // pre-scaled by QSCALE
    short* Kb  = (short*)(w + 16 * MB);
    short* Vb  = (short*)(w + 24 * MB);
    short* WT  = (short*)(w + 32 * MB);   // [3072][1024] bf16 (Wq^T|Wk^T|Wv^T)
    short* WgT = (short*)(w + 38 * MB);   // [1024][2048] bf16
    short* fb  = (short*)(w + 42 * MB);   // flowed bf16 [4096][1024]
    short* VT  = (short*)(w + 50 * MB);   // V^T per head [b*16+h][64 dv][2048 s]

    cvt_kernel<<<4096, 256, 0, stream>>>(x, xb, 4096 * 1024 / 4);
    dim3 tb(32, 8);
    transpose_bf16<<<dim3(32, 32), tb, 0, stream>>>(Wq, WT, 1024, 1024);
    transpose_bf16<<<dim3(32, 32), tb, 0, stream>>>(Wk, WT + 1024 * 1024, 1024, 1024);
    transpose_bf16<<<dim3(32, 32), tb, 0, stream>>>(Wv, WT + 2 * 1024 * 1024, 1024, 1024);
    transpose_bf16<<<dim3(32, 64), tb, 0, stream>>>(Wg, WgT, 2048, 1024);
    gemm_qkv<<<dim3(32, 24), 256, 0, stream>>>(xb, WT, bq, bk, bv, Qb, Kb, Vb);
    vtrans_kernel<<<dim3(64, 2, 32), tb, 0, stream>>>(Vb, VT);
    attn_kernel<<<1024, 256, 0, stream>>>(Qb, Kb, VT, fb);
    gemm_gate<<<dim3(32, 8), 256, 0, stream>>>(xb, fb, WgT, bg, x, out);
    ln_kernel<<<4096, 256, 0, stream>>>(out, gamma, beta);
}